// Round 1
// baseline (562.715 us; speedup 1.0000x reference)
//
#include <hip/hip_runtime.h>
#include <hip/hip_bf16.h>

#define N_NODES 100000
#define N_HEDGES 20000
#define N_EDGES 800000
#define HSEG (2 * N_HEDGES)            // 40000 hedge segments (t,h)
#define NSEG (2 * N_NODES)             // 200000 node segments (t,n)
#define MSEG (HSEG + NSEG)             // 240000 segments
#define NSUB 8                          // XCD-private sub-lists (blockIdx&7)
#define TOT (NSUB * MSEG)               // 1,920,000 counters
#define SCAN_BLOCKS ((TOT + 2047) / 2048)  // 938

#define CONV_PK (2 * 2 * 4 * 64 * 8)    // 8192 packed bf16 weights for k_conv
#define MIX_PK  (4 * 4 * 64 * 8)        // 8192 for k_mix
#define GRU_PK  (2 * 2 * 12 * 64 * 8)   // 24576 for k_gru

typedef __hip_bfloat16 bf16;
typedef __attribute__((ext_vector_type(8))) short bf16x8;
typedef __attribute__((ext_vector_type(4))) float f32x4;

__device__ __forceinline__ float b2f(bf16 v) { return __bfloat162float(v); }
__device__ __forceinline__ bf16 f2b(float v) { return __float2bfloat16(v); }
__device__ __forceinline__ short f2s(float v) {
    bf16 b = __float2bfloat16(v);
    return *reinterpret_cast<short*>(&b);
}
__device__ __forceinline__ bf16x8 pack8(float4 a, float4 b) {
    bf16x8 r = {f2s(a.x), f2s(a.y), f2s(a.z), f2s(a.w),
                f2s(b.x), f2s(b.y), f2s(b.z), f2s(b.w)};
    return r;
}
__device__ __forceinline__ float fast_sigmoid(float x) {
    return __builtin_amdgcn_rcpf(1.f + __expf(-x));
}
__device__ __forceinline__ float fast_tanh(float x) {
    return 1.f - 2.f * __builtin_amdgcn_rcpf(1.f + __expf(2.f * x));
}

// ---------------------------------------------------------------------------
// Pack all MFMA B-operand weights into LDS-ready bf16 layouts, once.
// Layouts replicate the per-kernel LDS pack index math exactly.
// ---------------------------------------------------------------------------
__global__ __launch_bounds__(256) void k_pack(const float* __restrict__ Wc,
                                              const float* __restrict__ Wm,
                                              const float* __restrict__ Wih,
                                              const float* __restrict__ Whh,
                                              bf16* __restrict__ conv_pk,
                                              bf16* __restrict__ mix_pk,
                                              bf16* __restrict__ gru_pk) {
    int idx = blockIdx.x * 256 + threadIdx.x;
    int stride = gridDim.x * 256;
    for (int i = idx; i < CONV_PK; i += stride) {
        int j = i & 7, ln = (i >> 3) & 63, r2 = i >> 9;
        int ct = r2 & 3, kt = (r2 >> 2) & 1, t = r2 >> 3;
        int k = kt * 32 + ((ln >> 4) << 3) + j;
        int n = ct * 16 + (ln & 15);
        conv_pk[i] = f2b(Wc[((size_t)t * 64 + k) * 64 + n]);
    }
    for (int i = idx; i < MIX_PK; i += stride) {
        int j = i & 7, ln = (i >> 3) & 63, r2 = i >> 9;
        int ct = r2 & 3, kt = r2 >> 2;
        int k = kt * 32 + ((ln >> 4) << 3) + j;
        int n = ct * 16 + (ln & 15);
        mix_pk[i] = f2b(Wm[(size_t)k * 64 + n]);
    }
    for (int i = idx; i < GRU_PK; i += stride) {
        int j = i & 7;
        int r = i >> 3;
        int ln = r & 63;
        int r2 = r >> 6;
        int ct = r2 % 12;
        int r3 = r2 / 12;
        int kt = r3 & 1;
        int mat = r3 >> 1;
        int k = kt * 32 + ((ln >> 4) << 3) + j;
        int n = ct * 16 + (ln & 15);
        float v = mat == 0 ? Wih[k * 192 + n] : Whh[k * 192 + n];
        gru_pk[i] = f2b(v);
    }
}

// ---------------------------------------------------------------------------
// MFMA conv: xl[t] = x @ W_conv[t], one wave per 16-row tile, both types.
// Weights arrive pre-packed: preload is a coalesced vector memcpy.
// ---------------------------------------------------------------------------
__global__ __launch_bounds__(256) void k_conv(const float* __restrict__ x,
                                              const bf16* __restrict__ conv_pk,
                                              bf16* __restrict__ xl) {
    __shared__ __align__(16) bf16 Wpk[CONV_PK];  // 16 KB
    {
        const bf16x8* src = (const bf16x8*)conv_pk;
        bf16x8* dst = (bf16x8*)Wpk;
        for (int i = threadIdx.x; i < CONV_PK / 8; i += 256) dst[i] = src[i];
    }
    __syncthreads();
    int wid = threadIdx.x >> 6, lane = threadIdx.x & 63;
    int quad = lane >> 4, l16 = lane & 15;
    int wave = blockIdx.x * 4 + wid, n_waves = gridDim.x * 4;
    const f32x4 zero = {0.f, 0.f, 0.f, 0.f};
    for (int tile = wave; tile < N_NODES / 16; tile += n_waves) {
        int row0 = tile * 16;
        const float* xp = x + (size_t)(row0 + l16) * 64 + quad * 8;
        bf16x8 a0 = pack8(*(const float4*)xp, *(const float4*)(xp + 4));
        bf16x8 a1 = pack8(*(const float4*)(xp + 32), *(const float4*)(xp + 36));
#define LDBC(t, kt, ct) (*(const bf16x8*)&Wpk[((((t)*2 + (kt)) * 4 + (ct)) * 64 + lane) * 8])
#pragma unroll
        for (int t = 0; t < 2; ++t) {
#pragma unroll
            for (int ct = 0; ct < 4; ++ct) {
                f32x4 acc = __builtin_amdgcn_mfma_f32_16x16x32_bf16(a0, LDBC(t, 0, ct), zero, 0, 0, 0);
                acc = __builtin_amdgcn_mfma_f32_16x16x32_bf16(a1, LDBC(t, 1, ct), acc, 0, 0, 0);
#pragma unroll
                for (int rg = 0; rg < 4; ++rg) {
                    int row = row0 + quad * 4 + rg;
                    xl[(size_t)t * N_NODES * 64 + (size_t)row * 64 + ct * 16 + l16] = f2b(acc[rg]);
                }
            }
        }
#undef LDBC
    }
}

// ---------------------------------------------------------------------------
// Histogram into XCD-private counters cnt[sub][seg], sub = blockIdx&7.
// ---------------------------------------------------------------------------
__global__ __launch_bounds__(256) void k_hist(const int* __restrict__ node_idx,
                                              const int* __restrict__ hedge_idx,
                                              const int* __restrict__ attr,
                                              int* __restrict__ cnt) {
    int e = blockIdx.x * 256 + threadIdx.x;
    int base = (blockIdx.x & (NSUB - 1)) * MSEG;
    if (e < N_EDGES) {
        int t = attr[e];
        atomicAdd(&cnt[base + t * N_HEDGES + hedge_idx[e]], 1);
        atomicAdd(&cnt[base + HSEG + t * N_NODES + node_idx[e]], 1);
    }
}

// ---------------------------------------------------------------------------
// Scan 1/3: 2048 elems/block (256 thr x 8), partial exclusive scan + bsum.
// ---------------------------------------------------------------------------
__global__ __launch_bounds__(256) void k_scan1(const int* __restrict__ cnt,
                                               int* __restrict__ off,
                                               int* __restrict__ bsum) {
    __shared__ int s[256];
    int base = blockIdx.x * 2048 + threadIdx.x * 8;
    int v[8];
    int tsum = 0;
#pragma unroll
    for (int j = 0; j < 8; ++j) {
        int g = base + j;
        v[j] = (g < TOT) ? cnt[g] : 0;
        tsum += v[j];
    }
    s[threadIdx.x] = tsum;
    __syncthreads();
    for (int o = 1; o < 256; o <<= 1) {
        int t = (threadIdx.x >= o) ? s[threadIdx.x - o] : 0;
        __syncthreads();
        s[threadIdx.x] += t;
        __syncthreads();
    }
    int run = s[threadIdx.x] - tsum;
#pragma unroll
    for (int j = 0; j < 8; ++j) {
        int g = base + j;
        if (g < TOT) off[g] = run;
        run += v[j];
    }
    if (threadIdx.x == 255) bsum[blockIdx.x] = s[255];
}

// ---------------------------------------------------------------------------
// Scan 2/3: exclusive scan of SCAN_BLOCKS (<=1024) block sums, one block.
// ---------------------------------------------------------------------------
__global__ __launch_bounds__(1024) void k_scan2(int* __restrict__ bsum) {
    __shared__ int s[1024];
    int tid = threadIdx.x;
    int v = (tid < SCAN_BLOCKS) ? bsum[tid] : 0;
    s[tid] = v;
    __syncthreads();
    for (int o = 1; o < 1024; o <<= 1) {
        int t = (tid >= o) ? s[tid - o] : 0;
        __syncthreads();
        s[tid] += t;
        __syncthreads();
    }
    if (tid < SCAN_BLOCKS) bsum[tid] = s[tid] - v;
}

// ---------------------------------------------------------------------------
// Scan 3/3: final off + cursor copy + TRANSPOSED offsets offT[seg][8].
// Sentinel row offT[MSEG][k] = off[(k+1)*MSEG].
// ---------------------------------------------------------------------------
__global__ __launch_bounds__(256) void k_scan3(int* __restrict__ off,
                                               const int* __restrict__ bsum,
                                               int* __restrict__ cursor,
                                               int* __restrict__ offT) {
    int base = blockIdx.x * 2048 + threadIdx.x * 8;
    int add = bsum[blockIdx.x];
#pragma unroll
    for (int j = 0; j < 8; ++j) {
        int g = base + j;
        if (g < TOT) {
            int v = off[g] + add;
            off[g] = v;
            cursor[g] = v;
            int k = g / MSEG, s = g - k * MSEG;
            offT[s * NSUB + k] = v;
            if (s == 0 && k > 0) offT[MSEG * NSUB + (k - 1)] = v;  // end of sub k-1
        }
    }
    if (base == 0) offT[MSEG * NSUB + 7] = 2 * N_EDGES;
}

// ---------------------------------------------------------------------------
// Scatter into XCD-private sub-lists (sub = blockIdx&7).
// ---------------------------------------------------------------------------
__global__ __launch_bounds__(256) void k_scatter(const int* __restrict__ node_idx,
                                                 const int* __restrict__ hedge_idx,
                                                 const int* __restrict__ attr,
                                                 int* __restrict__ cursor,
                                                 int* __restrict__ sortedAll) {
    int e = blockIdx.x * 256 + threadIdx.x;
    int base = (blockIdx.x & (NSUB - 1)) * MSEG;
    if (e < N_EDGES) {
        int t = attr[e], n = node_idx[e], h = hedge_idx[e];
        int p1 = atomicAdd(&cursor[base + t * N_HEDGES + h], 1);
        sortedAll[p1] = t * N_NODES + n;
        int p2 = atomicAdd(&cursor[base + HSEG + t * N_NODES + n], 1);
        sortedAll[p2] = t * N_HEDGES + h;
    }
}

// ---------------------------------------------------------------------------
// Quarter-per-segment gather: each 16-lane quarter owns one segment (4 per
// wave). One coalesced load ov = offT[seg0*8 + lane] provides all 4 quarters'
// 8 begs + 8 ends (offT rows contiguous: ends of s == begs of s+1). Uniform
// k-loop with per-quarter exact bounds via shfl — no clamped/masked loads.
// 16 lanes x 8B = one 128B row per quarter per iter; 4 independent gathers
// in flight per wave. Epilogue: lane owns feats 4*l16..+3 of its quarter's
// segment — all 64 lanes write one coalesced 512B store, NO cross-lane
// reduction.
// ---------------------------------------------------------------------------
__device__ __forceinline__ void seg_quarter(const int* __restrict__ offT,
                                            const int* __restrict__ sortedAll,
                                            const bf16* __restrict__ rows,
                                            int seg0, int lane,
                                            float acc[4], int* total) {
    int q = lane >> 4, l16 = lane & 15;
    int ov = offT[(size_t)seg0 * NSUB + lane];  // begs+ends for 4 quarters
    acc[0] = acc[1] = acc[2] = acc[3] = 0.f;
    int tot = 0;
#pragma unroll
    for (int k = 0; k < NSUB; ++k) {
        int myb = __shfl(ov, q * NSUB + k);
        int mye = __shfl(ov, q * NSUB + k + NSUB);
        tot += mye - myb;
        for (int i = myb; i < mye; ++i) {
            int idx = sortedAll[i];  // 16 lanes same addr (broadcast)
            uint2 v = *(const uint2*)(rows + (size_t)idx * 64 + l16 * 4);
            acc[0] += __uint_as_float(v.x << 16);
            acc[1] += __uint_as_float(v.x & 0xffff0000u);
            acc[2] += __uint_as_float(v.y << 16);
            acc[3] += __uint_as_float(v.y & 0xffff0000u);
        }
    }
    *total = tot;
}

// CSR node->hedge: ef[t][h] = (1/B) * sum xl rows. 16 segments per block.
__global__ __launch_bounds__(256) void k_ef2(const int* __restrict__ offT,
                                             const int* __restrict__ sortedAll,
                                             const bf16* __restrict__ xl,
                                             bf16* __restrict__ ef16) {
    int wid = threadIdx.x >> 6, lane = threadIdx.x & 63;
    int seg0 = (blockIdx.x * 4 + wid) * 4;
    if (seg0 >= HSEG) return;
    float acc[4];
    int tot;
    seg_quarter(offT, sortedAll, xl, seg0, lane, acc, &tot);
    float scale = tot > 0 ? 1.0f / (float)tot : 0.f;
    int s = seg0 + (lane >> 4), l16 = lane & 15;
    uint lo = (uint)(unsigned short)f2s(acc[0] * scale) |
              ((uint)(unsigned short)f2s(acc[1] * scale) << 16);
    uint hi = (uint)(unsigned short)f2s(acc[2] * scale) |
              ((uint)(unsigned short)f2s(acc[3] * scale) << 16);
    *(uint2*)(ef16 + (size_t)s * 64 + l16 * 4) = make_uint2(lo, hi);
}

// CSR hedge->node: mixin[t][n] = (1/D) * sum ef rows + b_conv[t].
__global__ __launch_bounds__(256) void k_no2(const int* __restrict__ offT,
                                             const int* __restrict__ sortedAll,
                                             const bf16* __restrict__ ef16,
                                             const float* __restrict__ bconv,
                                             bf16* __restrict__ mixin16) {
    int wid = threadIdx.x >> 6, lane = threadIdx.x & 63;
    int j0 = (blockIdx.x * 4 + wid) * 4;
    if (j0 >= NSEG) return;
    float acc[4];
    int tot;
    seg_quarter(offT, sortedAll, ef16, HSEG + j0, lane, acc, &tot);
    float scale = tot > 0 ? 1.0f / (float)tot : 0.f;
    int q = lane >> 4, l16 = lane & 15;
    int j = j0 + q;
    int t = (j >= N_NODES) ? 1 : 0;
    float4 bc = *(const float4*)&bconv[t * 64 + l16 * 4];
    uint lo = (uint)(unsigned short)f2s(acc[0] * scale + bc.x) |
              ((uint)(unsigned short)f2s(acc[1] * scale + bc.y) << 16);
    uint hi = (uint)(unsigned short)f2s(acc[2] * scale + bc.z) |
              ((uint)(unsigned short)f2s(acc[3] * scale + bc.w) << 16);
    *(uint2*)(mixin16 + (size_t)j * 64 + l16 * 4) = make_uint2(lo, hi);
}

// ---------------------------------------------------------------------------
// MFMA mix: h = relu(mixin @ W_mix + b_mix), bf16 out. K=128 (4 k-frags).
// ---------------------------------------------------------------------------
__global__ __launch_bounds__(256) void k_mix(const bf16* __restrict__ mixin16,
                                             const bf16* __restrict__ mix_pk,
                                             const float* __restrict__ bm_g,
                                             bf16* __restrict__ hbuf16) {
    __shared__ __align__(16) bf16 Wpk[MIX_PK];  // 16 KB
    {
        const bf16x8* src = (const bf16x8*)mix_pk;
        bf16x8* dst = (bf16x8*)Wpk;
        for (int i = threadIdx.x; i < MIX_PK / 8; i += 256) dst[i] = src[i];
    }
    __syncthreads();
    int wid = threadIdx.x >> 6, lane = threadIdx.x & 63;
    int quad = lane >> 4, l16 = lane & 15;
    float bmv[4];
#pragma unroll
    for (int ct = 0; ct < 4; ++ct) bmv[ct] = bm_g[ct * 16 + l16];

    int wave = blockIdx.x * 4 + wid, n_waves = gridDim.x * 4;
    for (int tile = wave; tile < N_NODES / 16; tile += n_waves) {
        int row0 = tile * 16;
        int arow = row0 + l16;
        bf16x8 af[4];
#pragma unroll
        for (int kt = 0; kt < 4; ++kt) {
            const bf16* src = (kt < 2)
                ? mixin16 + (size_t)arow * 64 + kt * 32 + quad * 8
                : mixin16 + ((size_t)N_NODES + arow) * 64 + (kt - 2) * 32 + quad * 8;
            af[kt] = *(const bf16x8*)src;
        }
#define LDBM(kt, ct) (*(const bf16x8*)&Wpk[(((kt)*4 + (ct)) * 64 + lane) * 8])
#pragma unroll
        for (int ct = 0; ct < 4; ++ct) {
            f32x4 acc = {bmv[ct], bmv[ct], bmv[ct], bmv[ct]};
#pragma unroll
            for (int kt = 0; kt < 4; ++kt)
                acc = __builtin_amdgcn_mfma_f32_16x16x32_bf16(af[kt], LDBM(kt, ct), acc, 0, 0, 0);
#pragma unroll
            for (int rg = 0; rg < 4; ++rg) {
                int row = row0 + quad * 4 + rg;
                hbuf16[(size_t)row * 64 + ct * 16 + l16] = f2b(fmaxf(acc[rg], 0.f));
            }
        }
#undef LDBM
    }
}

// ---------------------------------------------------------------------------
// MFMA GRU: one wave per 16-row tile; h_prev cast fp32->bf16 inline.
// Biases folded into MFMA C-init (bias depends only on output column ->
// splat across the 4 row-regs is exact). Fast sigmoid/tanh via v_exp+v_rcp.
// __launch_bounds__(256,3): force <=168 VGPR so 3 waves/SIMD fit (LDS 48KB
// allows 3 blocks/CU); grid 768 = 3 blocks/CU.
// ---------------------------------------------------------------------------
#define GRU_TILES (N_NODES / 16)
__global__ __launch_bounds__(256, 3) void k_gru(const bf16* __restrict__ gru_pk,
                                                const bf16* __restrict__ hbuf16,
                                                const float* __restrict__ h_prev,
                                                const float* __restrict__ bih_g,
                                                const float* __restrict__ bhh_g,
                                                const float* __restrict__ Wro_g,
                                                const float* __restrict__ bro_g,
                                                float* __restrict__ out_h,
                                                float* __restrict__ out_o) {
    __shared__ __align__(16) bf16 Wpk[GRU_PK];  // 48 KB
    {
        const bf16x8* src = (const bf16x8*)gru_pk;
        bf16x8* dst = (bf16x8*)Wpk;
        for (int i = threadIdx.x; i < GRU_PK / 8; i += 256) dst[i] = src[i];
    }
    __syncthreads();

    int wid = threadIdx.x >> 6, lane = threadIdx.x & 63;
    int quad = lane >> 4, l16 = lane & 15;

    // Combined biases per output column (depend on l16 only):
    //   r,z gates: b_ih + b_hh fused; n gate: b_ih_n into gi, b_hh_n into gh.
    float br_c[4], bz_c[4], bin_c[4], bhn_c[4], wv[4][3];
#pragma unroll
    for (int cc = 0; cc < 4; ++cc) {
        int col = cc * 16 + l16;
        br_c[cc] = bih_g[col] + bhh_g[col];
        bz_c[cc] = bih_g[64 + col] + bhh_g[64 + col];
        bin_c[cc] = bih_g[128 + col];
        bhn_c[cc] = bhh_g[128 + col];
        wv[cc][0] = Wro_g[col * 64 + 0];
        wv[cc][1] = Wro_g[col * 64 + 1];
        wv[cc][2] = Wro_g[col * 64 + 2];
    }
    float bro0 = bro_g[0], bro1 = bro_g[1], bro2 = bro_g[2];

    int wave = blockIdx.x * 4 + wid;
    int n_waves = gridDim.x * 4;
    const f32x4 zero = {0.f, 0.f, 0.f, 0.f};

    for (int tile = wave; tile < GRU_TILES; tile += n_waves) {
        int row0 = tile * 16;
        const bf16* ha_p = hbuf16 + (size_t)(row0 + l16) * 64 + quad * 8;
        bf16x8 ha0 = *(const bf16x8*)ha_p;
        bf16x8 ha1 = *(const bf16x8*)(ha_p + 32);
        const float* pp = h_prev + (size_t)(row0 + l16) * 64 + quad * 8;
        bf16x8 pa0 = pack8(*(const float4*)pp, *(const float4*)(pp + 4));
        bf16x8 pa1 = pack8(*(const float4*)(pp + 32), *(const float4*)(pp + 36));

        float p[4][3];
#pragma unroll
        for (int rg = 0; rg < 4; ++rg) p[rg][0] = p[rg][1] = p[rg][2] = 0.f;

#pragma unroll
        for (int cc = 0; cc < 4; ++cc) {
#define LDB(mat, kt, ct) (*(const bf16x8*)&Wpk[((((mat)*2 + (kt)) * 12 + (ct)) * 64 + lane) * 8])
            f32x4 bR = {br_c[cc], br_c[cc], br_c[cc], br_c[cc]};
            f32x4 bZ = {bz_c[cc], bz_c[cc], bz_c[cc], bz_c[cc]};
            f32x4 bIN = {bin_c[cc], bin_c[cc], bin_c[cc], bin_c[cc]};
            f32x4 bHN = {bhn_c[cc], bhn_c[cc], bhn_c[cc], bhn_c[cc]};
            f32x4 gir = __builtin_amdgcn_mfma_f32_16x16x32_bf16(ha0, LDB(0, 0, cc), bR, 0, 0, 0);
            gir = __builtin_amdgcn_mfma_f32_16x16x32_bf16(ha1, LDB(0, 1, cc), gir, 0, 0, 0);
            f32x4 giz = __builtin_amdgcn_mfma_f32_16x16x32_bf16(ha0, LDB(0, 0, cc + 4), bZ, 0, 0, 0);
            giz = __builtin_amdgcn_mfma_f32_16x16x32_bf16(ha1, LDB(0, 1, cc + 4), giz, 0, 0, 0);
            f32x4 gin = __builtin_amdgcn_mfma_f32_16x16x32_bf16(ha0, LDB(0, 0, cc + 8), bIN, 0, 0, 0);
            gin = __builtin_amdgcn_mfma_f32_16x16x32_bf16(ha1, LDB(0, 1, cc + 8), gin, 0, 0, 0);
            f32x4 ghr = __builtin_amdgcn_mfma_f32_16x16x32_bf16(pa0, LDB(1, 0, cc), zero, 0, 0, 0);
            ghr = __builtin_amdgcn_mfma_f32_16x16x32_bf16(pa1, LDB(1, 1, cc), ghr, 0, 0, 0);
            f32x4 ghz = __builtin_amdgcn_mfma_f32_16x16x32_bf16(pa0, LDB(1, 0, cc + 4), zero, 0, 0, 0);
            ghz = __builtin_amdgcn_mfma_f32_16x16x32_bf16(pa1, LDB(1, 1, cc + 4), ghz, 0, 0, 0);
            f32x4 ghn = __builtin_amdgcn_mfma_f32_16x16x32_bf16(pa0, LDB(1, 0, cc + 8), bHN, 0, 0, 0);
            ghn = __builtin_amdgcn_mfma_f32_16x16x32_bf16(pa1, LDB(1, 1, cc + 8), ghn, 0, 0, 0);
#undef LDB
#pragma unroll
            for (int rg = 0; rg < 4; ++rg) {
                int row = row0 + quad * 4 + rg;
                float pv = h_prev[(size_t)row * 64 + cc * 16 + l16];
                float rr = fast_sigmoid(gir[rg] + ghr[rg]);
                float zz = fast_sigmoid(giz[rg] + ghz[rg]);
                float nn = fast_tanh(gin[rg] + rr * ghn[rg]);
                float hn = (1.f - zz) * nn + zz * pv;
                out_h[(size_t)row * 64 + cc * 16 + l16] = hn;
                p[rg][0] += hn * wv[cc][0];
                p[rg][1] += hn * wv[cc][1];
                p[rg][2] += hn * wv[cc][2];
            }
        }
#pragma unroll
        for (int rg = 0; rg < 4; ++rg) {
#pragma unroll
            for (int m = 1; m < 16; m <<= 1) {
                p[rg][0] += __shfl_xor(p[rg][0], m);
                p[rg][1] += __shfl_xor(p[rg][1], m);
                p[rg][2] += __shfl_xor(p[rg][2], m);
            }
        }
        if (l16 == 0) {
#pragma unroll
            for (int rg = 0; rg < 4; ++rg) {
                int row = row0 + quad * 4 + rg;
                out_o[(size_t)row * 3 + 0] = p[rg][0] + bro0;
                out_o[(size_t)row * 3 + 1] = p[rg][1] + bro1;
                out_o[(size_t)row * 3 + 2] = p[rg][2] + bro2;
            }
        }
    }
}

extern "C" void kernel_launch(void* const* d_in, const int* in_sizes, int n_in,
                              void* d_out, int out_size, void* d_ws, size_t ws_size,
                              hipStream_t stream) {
    const float* x        = (const float*)d_in[0];
    const float* h_prev   = (const float*)d_in[1];
    const int* node_idx   = (const int*)d_in[2];
    const int* hedge_idx  = (const int*)d_in[3];
    const int* edge_attr  = (const int*)d_in[4];
    const float* W_conv   = (const float*)d_in[5];
    const float* b_conv   = (const float*)d_in[6];
    const float* W_mix    = (const float*)d_in[7];
    const float* b_mix    = (const float*)d_in[8];
    const float* W_ih     = (const float*)d_in[9];
    const float* W_hh     = (const float*)d_in[10];
    const float* b_ih     = (const float*)d_in[11];
    const float* b_hh     = (const float*)d_in[12];
    const float* W_ro     = (const float*)d_in[13];
    const float* b_ro     = (const float*)d_in[14];

    char* p = (char*)d_ws;
    auto alloc = [&](size_t bytes) {
        char* r = p;
        p += (bytes + 63) & ~(size_t)63;
        return r;
    };
    int* cnt       = (int*)alloc((size_t)TOT * 4);        // [zeroed]
    int* off       = (int*)alloc((size_t)(TOT + 1) * 4);
    int* cursor    = (int*)alloc((size_t)TOT * 4);
    int* offT      = (int*)alloc((size_t)(MSEG + 1) * NSUB * 4);
    int* bsum      = (int*)alloc(1024 * 4);
    int* sortedAll = (int*)alloc((size_t)2 * N_EDGES * 4);
    bf16* xl       = (bf16*)alloc((size_t)2 * N_NODES * 64 * 2);
    bf16* ef16     = (bf16*)alloc((size_t)HSEG * 64 * 2);
    bf16* hbuf16   = (bf16*)alloc((size_t)N_NODES * 64 * 2);
    bf16* conv_pk  = (bf16*)alloc((size_t)CONV_PK * 2);
    bf16* mix_pk   = (bf16*)alloc((size_t)MIX_PK * 2);
    bf16* gru_pk   = (bf16*)alloc((size_t)GRU_PK * 2);
    bf16* mixin16  = xl;  // alias: xl dead after k_ef2

    hipMemsetAsync(cnt, 0, (size_t)TOT * 4, stream);

    float* out_h = (float*)d_out;
    float* out_o = out_h + (size_t)N_NODES * 64;

    k_pack<<<16, 256, 0, stream>>>(W_conv, W_mix, W_ih, W_hh, conv_pk, mix_pk, gru_pk);
    k_conv<<<1024, 256, 0, stream>>>(x, conv_pk, xl);
    k_hist<<<(N_EDGES + 255) / 256, 256, 0, stream>>>(node_idx, hedge_idx, edge_attr, cnt);
    k_scan1<<<SCAN_BLOCKS, 256, 0, stream>>>(cnt, off, bsum);
    k_scan2<<<1, 1024, 0, stream>>>(bsum);
    k_scan3<<<SCAN_BLOCKS, 256, 0, stream>>>(off, bsum, cursor, offT);
    k_scatter<<<(N_EDGES + 255) / 256, 256, 0, stream>>>(node_idx, hedge_idx, edge_attr,
                                                         cursor, sortedAll);
    k_ef2<<<HSEG / 16, 256, 0, stream>>>(offT, sortedAll, xl, ef16);
    k_no2<<<NSEG / 16, 256, 0, stream>>>(offT, sortedAll, ef16, b_conv, mixin16);
    k_mix<<<1024, 256, 0, stream>>>(mixin16, mix_pk, b_mix, hbuf16);
    k_gru<<<768, 256, 0, stream>>>(gru_pk, hbuf16, h_prev, b_ih, b_hh,
                                   W_ro, b_ro, out_h, out_o);
}

// Round 2
// 462.265 us; speedup vs baseline: 1.2173x; 1.2173x over previous
//
#include <hip/hip_runtime.h>
#include <hip/hip_bf16.h>

#define N_NODES 100000
#define N_HEDGES 20000
#define N_EDGES 800000
#define HSEG (2 * N_HEDGES)            // 40000 hedge segments (t,h)
#define NSEG (2 * N_NODES)             // 200000 node segments (t,n)
#define MSEG (HSEG + NSEG)             // 240000 segments
#define NSUB 8                          // XCD-private sub-lists (blockIdx&7)
#define TOT (NSUB * MSEG)               // 1,920,000 counters
#define SCAN_BLOCKS ((TOT + 2047) / 2048)  // 938

#define MIX_PK  (4 * 4 * 64 * 8)        // 8192 packed bf16 fused-mix weights
#define GRU_PK  (2 * 2 * 12 * 64 * 8)   // 24576 for k_gru

typedef __hip_bfloat16 bf16;
typedef __attribute__((ext_vector_type(8))) short bf16x8;
typedef __attribute__((ext_vector_type(4))) float f32x4;

__device__ __forceinline__ float b2f(bf16 v) { return __bfloat162float(v); }
__device__ __forceinline__ bf16 f2b(float v) { return __float2bfloat16(v); }
__device__ __forceinline__ short f2s(float v) {
    bf16 b = __float2bfloat16(v);
    return *reinterpret_cast<short*>(&b);
}
__device__ __forceinline__ bf16x8 pack8(float4 a, float4 b) {
    bf16x8 r = {f2s(a.x), f2s(a.y), f2s(a.z), f2s(a.w),
                f2s(b.x), f2s(b.y), f2s(b.z), f2s(b.w)};
    return r;
}
__device__ __forceinline__ float fast_sigmoid(float x) {
    return __builtin_amdgcn_rcpf(1.f + __expf(-x));
}
__device__ __forceinline__ float fast_tanh(float x) {
    return 1.f - 2.f * __builtin_amdgcn_rcpf(1.f + __expf(2.f * x));
}

// ---------------------------------------------------------------------------
// Pack GRU weights into LDS layout; compute FUSED mix weights on device:
//   Wf[t] = W_conv[t] @ W_mix[t*64:(t+1)*64, :]   (64x64 each, f32 dot, bf16)
//   bfused = b_mix + sum_t b_conv[t] @ W_mix_t
// Conv+mix algebra: Dinv H (Binv H^T (xW)) Wm = (Dinv H Binv H^T x)(W Wm),
// so raw-x aggregation + one fused GEMM replaces k_conv + k_mix weights.
// ---------------------------------------------------------------------------
__global__ __launch_bounds__(256) void k_pack(const float* __restrict__ Wc,
                                              const float* __restrict__ Wm,
                                              const float* __restrict__ bc,
                                              const float* __restrict__ bm,
                                              const float* __restrict__ Wih,
                                              const float* __restrict__ Whh,
                                              bf16* __restrict__ gru_pk,
                                              bf16* __restrict__ mixf_pk,
                                              float* __restrict__ bfused) {
    int idx = blockIdx.x * 256 + threadIdx.x;
    int stride = gridDim.x * 256;
    for (int i = idx; i < GRU_PK; i += stride) {
        int j = i & 7;
        int r = i >> 3;
        int ln = r & 63;
        int r2 = r >> 6;
        int ct = r2 % 12;
        int r3 = r2 / 12;
        int kt = r3 & 1;
        int mat = r3 >> 1;
        int k = kt * 32 + ((ln >> 4) << 3) + j;
        int n = ct * 16 + (ln & 15);
        float v = mat == 0 ? Wih[k * 192 + n] : Whh[k * 192 + n];
        gru_pk[i] = f2b(v);
    }
    for (int i = idx; i < MIX_PK; i += stride) {
        int j = i & 7, ln = (i >> 3) & 63, r2 = i >> 9;
        int ct = r2 & 3, kt = r2 >> 2;
        int k = kt * 32 + ((ln >> 4) << 3) + j;   // 0..127 (concat dim)
        int n = ct * 16 + (ln & 15);
        int t = k >> 6, kk = k & 63;
        float s = 0.f;
        for (int q = 0; q < 64; ++q)
            s += Wc[((size_t)t * 64 + kk) * 64 + q] * Wm[(size_t)(t * 64 + q) * 64 + n];
        mixf_pk[i] = f2b(s);
    }
    for (int i = idx; i < 64; i += stride) {
        float s = bm[i];
        for (int q = 0; q < 64; ++q)
            s += bc[q] * Wm[(size_t)q * 64 + i] + bc[64 + q] * Wm[(size_t)(64 + q) * 64 + i];
        bfused[i] = s;
    }
}

// ---------------------------------------------------------------------------
// Cast x to bf16 once; gathers then read 128B rows shared by both types.
// ---------------------------------------------------------------------------
__global__ __launch_bounds__(256) void k_cast(const float* __restrict__ x,
                                              bf16* __restrict__ xb) {
    size_t i = ((size_t)blockIdx.x * 256 + threadIdx.x) * 8;
    const float* xp = x + i;
    float4 a = *(const float4*)xp;
    float4 b = *(const float4*)(xp + 4);
    *(bf16x8*)(xb + i) = pack8(a, b);
}

// ---------------------------------------------------------------------------
// Histogram into XCD-private counters cnt[sub][seg], sub = blockIdx&7.
// ---------------------------------------------------------------------------
__global__ __launch_bounds__(256) void k_hist(const int* __restrict__ node_idx,
                                              const int* __restrict__ hedge_idx,
                                              const int* __restrict__ attr,
                                              int* __restrict__ cnt) {
    int e = blockIdx.x * 256 + threadIdx.x;
    int base = (blockIdx.x & (NSUB - 1)) * MSEG;
    if (e < N_EDGES) {
        int t = attr[e];
        atomicAdd(&cnt[base + t * N_HEDGES + hedge_idx[e]], 1);
        atomicAdd(&cnt[base + HSEG + t * N_NODES + node_idx[e]], 1);
    }
}

// ---------------------------------------------------------------------------
// Scan 1/3: 2048 elems/block (256 thr x 8), partial exclusive scan + bsum.
// ---------------------------------------------------------------------------
__global__ __launch_bounds__(256) void k_scan1(const int* __restrict__ cnt,
                                               int* __restrict__ off,
                                               int* __restrict__ bsum) {
    __shared__ int s[256];
    int base = blockIdx.x * 2048 + threadIdx.x * 8;
    int v[8];
    int tsum = 0;
#pragma unroll
    for (int j = 0; j < 8; ++j) {
        int g = base + j;
        v[j] = (g < TOT) ? cnt[g] : 0;
        tsum += v[j];
    }
    s[threadIdx.x] = tsum;
    __syncthreads();
    for (int o = 1; o < 256; o <<= 1) {
        int t = (threadIdx.x >= o) ? s[threadIdx.x - o] : 0;
        __syncthreads();
        s[threadIdx.x] += t;
        __syncthreads();
    }
    int run = s[threadIdx.x] - tsum;
#pragma unroll
    for (int j = 0; j < 8; ++j) {
        int g = base + j;
        if (g < TOT) off[g] = run;
        run += v[j];
    }
    if (threadIdx.x == 255) bsum[blockIdx.x] = s[255];
}

// ---------------------------------------------------------------------------
// Scan 2/3: exclusive scan of SCAN_BLOCKS (<=1024) block sums, one block.
// ---------------------------------------------------------------------------
__global__ __launch_bounds__(1024) void k_scan2(int* __restrict__ bsum) {
    __shared__ int s[1024];
    int tid = threadIdx.x;
    int v = (tid < SCAN_BLOCKS) ? bsum[tid] : 0;
    s[tid] = v;
    __syncthreads();
    for (int o = 1; o < 1024; o <<= 1) {
        int t = (tid >= o) ? s[tid - o] : 0;
        __syncthreads();
        s[tid] += t;
        __syncthreads();
    }
    if (tid < SCAN_BLOCKS) bsum[tid] = s[tid] - v;
}

// ---------------------------------------------------------------------------
// Scan 3/3: final off + cursor copy + TRANSPOSED offsets offT[seg][8].
// Sentinel row offT[MSEG][k] = off[(k+1)*MSEG].
// ---------------------------------------------------------------------------
__global__ __launch_bounds__(256) void k_scan3(int* __restrict__ off,
                                               const int* __restrict__ bsum,
                                               int* __restrict__ cursor,
                                               int* __restrict__ offT) {
    int base = blockIdx.x * 2048 + threadIdx.x * 8;
    int add = bsum[blockIdx.x];
#pragma unroll
    for (int j = 0; j < 8; ++j) {
        int g = base + j;
        if (g < TOT) {
            int v = off[g] + add;
            off[g] = v;
            cursor[g] = v;
            int k = g / MSEG, s = g - k * MSEG;
            offT[s * NSUB + k] = v;
            if (s == 0 && k > 0) offT[MSEG * NSUB + (k - 1)] = v;  // end of sub k-1
        }
    }
    if (base == 0) offT[MSEG * NSUB + 7] = 2 * N_EDGES;
}

// ---------------------------------------------------------------------------
// Scatter into XCD-private sub-lists (sub = blockIdx&7).
// Hedge-side list stores bare node id (xb rows are type-shared now).
// ---------------------------------------------------------------------------
__global__ __launch_bounds__(256) void k_scatter(const int* __restrict__ node_idx,
                                                 const int* __restrict__ hedge_idx,
                                                 const int* __restrict__ attr,
                                                 int* __restrict__ cursor,
                                                 int* __restrict__ sortedAll) {
    int e = blockIdx.x * 256 + threadIdx.x;
    int base = (blockIdx.x & (NSUB - 1)) * MSEG;
    if (e < N_EDGES) {
        int t = attr[e], n = node_idx[e], h = hedge_idx[e];
        int p1 = atomicAdd(&cursor[base + t * N_HEDGES + h], 1);
        sortedAll[p1] = n;
        int p2 = atomicAdd(&cursor[base + HSEG + t * N_NODES + n], 1);
        sortedAll[p2] = t * N_HEDGES + h;
    }
}

// ---------------------------------------------------------------------------
// Quarter-per-segment gather: each 16-lane quarter owns one segment (4 per
// wave). One coalesced load ov = offT[seg0*8 + lane] provides all 4 quarters'
// 8 begs + 8 ends. Uniform k-loop with per-quarter exact bounds via shfl.
// 16 lanes x 8B = one 128B row per quarter per iter. Epilogue: one coalesced
// 512B store per wave, no cross-lane reduction.
// ---------------------------------------------------------------------------
__device__ __forceinline__ void seg_quarter(const int* __restrict__ offT,
                                            const int* __restrict__ sortedAll,
                                            const bf16* __restrict__ rows,
                                            int seg0, int lane,
                                            float acc[4], int* total) {
    int q = lane >> 4, l16 = lane & 15;
    int ov = offT[(size_t)seg0 * NSUB + lane];  // begs+ends for 4 quarters
    acc[0] = acc[1] = acc[2] = acc[3] = 0.f;
    int tot = 0;
#pragma unroll
    for (int k = 0; k < NSUB; ++k) {
        int myb = __shfl(ov, q * NSUB + k);
        int mye = __shfl(ov, q * NSUB + k + NSUB);
        tot += mye - myb;
        for (int i = myb; i < mye; ++i) {
            int idx = sortedAll[i];  // 16 lanes same addr (broadcast)
            uint2 v = *(const uint2*)(rows + (size_t)idx * 64 + l16 * 4);
            acc[0] += __uint_as_float(v.x << 16);
            acc[1] += __uint_as_float(v.x & 0xffff0000u);
            acc[2] += __uint_as_float(v.y << 16);
            acc[3] += __uint_as_float(v.y & 0xffff0000u);
        }
    }
    *total = tot;
}

// CSR node->hedge: ef_raw[t][h] = (1/B) * sum xb rows (RAW x, no weights).
__global__ __launch_bounds__(256) void k_ef2(const int* __restrict__ offT,
                                             const int* __restrict__ sortedAll,
                                             const bf16* __restrict__ xb,
                                             bf16* __restrict__ ef16) {
    int wid = threadIdx.x >> 6, lane = threadIdx.x & 63;
    int seg0 = (blockIdx.x * 4 + wid) * 4;
    if (seg0 >= HSEG) return;
    float acc[4];
    int tot;
    seg_quarter(offT, sortedAll, xb, seg0, lane, acc, &tot);
    float scale = tot > 0 ? 1.0f / (float)tot : 0.f;
    int s = seg0 + (lane >> 4), l16 = lane & 15;
    uint lo = (uint)(unsigned short)f2s(acc[0] * scale) |
              ((uint)(unsigned short)f2s(acc[1] * scale) << 16);
    uint hi = (uint)(unsigned short)f2s(acc[2] * scale) |
              ((uint)(unsigned short)f2s(acc[3] * scale) << 16);
    *(uint2*)(ef16 + (size_t)s * 64 + l16 * 4) = make_uint2(lo, hi);
}

// CSR hedge->node: agg[t][n] = (1/D) * sum ef_raw rows. Bias folded into
// bfused (k_mix), so no add here.
__global__ __launch_bounds__(256) void k_no2(const int* __restrict__ offT,
                                             const int* __restrict__ sortedAll,
                                             const bf16* __restrict__ ef16,
                                             bf16* __restrict__ agg16) {
    int wid = threadIdx.x >> 6, lane = threadIdx.x & 63;
    int j0 = (blockIdx.x * 4 + wid) * 4;
    if (j0 >= NSEG) return;
    float acc[4];
    int tot;
    seg_quarter(offT, sortedAll, ef16, HSEG + j0, lane, acc, &tot);
    float scale = tot > 0 ? 1.0f / (float)tot : 0.f;
    int q = lane >> 4, l16 = lane & 15;
    int j = j0 + q;
    uint lo = (uint)(unsigned short)f2s(acc[0] * scale) |
              ((uint)(unsigned short)f2s(acc[1] * scale) << 16);
    uint hi = (uint)(unsigned short)f2s(acc[2] * scale) |
              ((uint)(unsigned short)f2s(acc[3] * scale) << 16);
    *(uint2*)(agg16 + (size_t)j * 64 + l16 * 4) = make_uint2(lo, hi);
}

// ---------------------------------------------------------------------------
// MFMA mix (fused): h = relu([agg0|agg1] @ Wf + bfused), K=128 (4 k-frags).
// ---------------------------------------------------------------------------
__global__ __launch_bounds__(256) void k_mix(const bf16* __restrict__ agg16,
                                             const bf16* __restrict__ mixf_pk,
                                             const float* __restrict__ bfused,
                                             bf16* __restrict__ hbuf16) {
    __shared__ __align__(16) bf16 Wpk[MIX_PK];  // 16 KB
    {
        const bf16x8* src = (const bf16x8*)mixf_pk;
        bf16x8* dst = (bf16x8*)Wpk;
        for (int i = threadIdx.x; i < MIX_PK / 8; i += 256) dst[i] = src[i];
    }
    __syncthreads();
    int wid = threadIdx.x >> 6, lane = threadIdx.x & 63;
    int quad = lane >> 4, l16 = lane & 15;
    float bmv[4];
#pragma unroll
    for (int ct = 0; ct < 4; ++ct) bmv[ct] = bfused[ct * 16 + l16];

    int wave = blockIdx.x * 4 + wid, n_waves = gridDim.x * 4;
    for (int tile = wave; tile < N_NODES / 16; tile += n_waves) {
        int row0 = tile * 16;
        int arow = row0 + l16;
        bf16x8 af[4];
#pragma unroll
        for (int kt = 0; kt < 4; ++kt) {
            const bf16* src = (kt < 2)
                ? agg16 + (size_t)arow * 64 + kt * 32 + quad * 8
                : agg16 + ((size_t)N_NODES + arow) * 64 + (kt - 2) * 32 + quad * 8;
            af[kt] = *(const bf16x8*)src;
        }
#define LDBM(kt, ct) (*(const bf16x8*)&Wpk[(((kt)*4 + (ct)) * 64 + lane) * 8])
#pragma unroll
        for (int ct = 0; ct < 4; ++ct) {
            f32x4 acc = {bmv[ct], bmv[ct], bmv[ct], bmv[ct]};
#pragma unroll
            for (int kt = 0; kt < 4; ++kt)
                acc = __builtin_amdgcn_mfma_f32_16x16x32_bf16(af[kt], LDBM(kt, ct), acc, 0, 0, 0);
#pragma unroll
            for (int rg = 0; rg < 4; ++rg) {
                int row = row0 + quad * 4 + rg;
                hbuf16[(size_t)row * 64 + ct * 16 + l16] = f2b(fmaxf(acc[rg], 0.f));
            }
        }
#undef LDBM
    }
}

// ---------------------------------------------------------------------------
// MFMA GRU. Gate fusion: r = sigmoid(gi_r + gh_r) -> ONE accumulator chain of
// 4 MFMAs (ha0,ha1,pa0,pa1); same for z. Only the n gate needs separate
// gi_n / gh_n (because of r * gh_n). Live accumulators per cc: 6 -> 4,
// cutting VGPR demand so 3 waves/SIMD fit NATURALLY (no forced bound —
// round-1's __launch_bounds__(256,3) clamped to 84 VGPR and spilled 360MB
// to scratch). Biases in MFMA C-init; fast sigmoid/tanh via v_exp+v_rcp.
// ---------------------------------------------------------------------------
#define GRU_TILES (N_NODES / 16)
__global__ __launch_bounds__(256) void k_gru(const bf16* __restrict__ gru_pk,
                                             const bf16* __restrict__ hbuf16,
                                             const float* __restrict__ h_prev,
                                             const float* __restrict__ bih_g,
                                             const float* __restrict__ bhh_g,
                                             const float* __restrict__ Wro_g,
                                             const float* __restrict__ bro_g,
                                             float* __restrict__ out_h,
                                             float* __restrict__ out_o) {
    __shared__ __align__(16) bf16 Wpk[GRU_PK];  // 48 KB
    {
        const bf16x8* src = (const bf16x8*)gru_pk;
        bf16x8* dst = (bf16x8*)Wpk;
        for (int i = threadIdx.x; i < GRU_PK / 8; i += 256) dst[i] = src[i];
    }
    __syncthreads();

    int wid = threadIdx.x >> 6, lane = threadIdx.x & 63;
    int quad = lane >> 4, l16 = lane & 15;

    float br_c[4], bz_c[4], bin_c[4], bhn_c[4], wv[4][3];
#pragma unroll
    for (int cc = 0; cc < 4; ++cc) {
        int col = cc * 16 + l16;
        br_c[cc] = bih_g[col] + bhh_g[col];
        bz_c[cc] = bih_g[64 + col] + bhh_g[64 + col];
        bin_c[cc] = bih_g[128 + col];
        bhn_c[cc] = bhh_g[128 + col];
        wv[cc][0] = Wro_g[col * 64 + 0];
        wv[cc][1] = Wro_g[col * 64 + 1];
        wv[cc][2] = Wro_g[col * 64 + 2];
    }
    float bro0 = bro_g[0], bro1 = bro_g[1], bro2 = bro_g[2];

    int wave = blockIdx.x * 4 + wid;
    int n_waves = gridDim.x * 4;

    for (int tile = wave; tile < GRU_TILES; tile += n_waves) {
        int row0 = tile * 16;
        const bf16* ha_p = hbuf16 + (size_t)(row0 + l16) * 64 + quad * 8;
        bf16x8 ha0 = *(const bf16x8*)ha_p;
        bf16x8 ha1 = *(const bf16x8*)(ha_p + 32);
        const float* pp = h_prev + (size_t)(row0 + l16) * 64 + quad * 8;
        bf16x8 pa0 = pack8(*(const float4*)pp, *(const float4*)(pp + 4));
        bf16x8 pa1 = pack8(*(const float4*)(pp + 32), *(const float4*)(pp + 36));

        float p[4][3];
#pragma unroll
        for (int rg = 0; rg < 4; ++rg) p[rg][0] = p[rg][1] = p[rg][2] = 0.f;

#pragma unroll
        for (int cc = 0; cc < 4; ++cc) {
#define LDB(mat, kt, ct) (*(const bf16x8*)&Wpk[((((mat)*2 + (kt)) * 12 + (ct)) * 64 + lane) * 8])
            f32x4 rs = {br_c[cc], br_c[cc], br_c[cc], br_c[cc]};
            f32x4 zs = {bz_c[cc], bz_c[cc], bz_c[cc], bz_c[cc]};
            f32x4 gin = {bin_c[cc], bin_c[cc], bin_c[cc], bin_c[cc]};
            f32x4 ghn = {bhn_c[cc], bhn_c[cc], bhn_c[cc], bhn_c[cc]};
            rs = __builtin_amdgcn_mfma_f32_16x16x32_bf16(ha0, LDB(0, 0, cc), rs, 0, 0, 0);
            rs = __builtin_amdgcn_mfma_f32_16x16x32_bf16(ha1, LDB(0, 1, cc), rs, 0, 0, 0);
            rs = __builtin_amdgcn_mfma_f32_16x16x32_bf16(pa0, LDB(1, 0, cc), rs, 0, 0, 0);
            rs = __builtin_amdgcn_mfma_f32_16x16x32_bf16(pa1, LDB(1, 1, cc), rs, 0, 0, 0);
            zs = __builtin_amdgcn_mfma_f32_16x16x32_bf16(ha0, LDB(0, 0, cc + 4), zs, 0, 0, 0);
            zs = __builtin_amdgcn_mfma_f32_16x16x32_bf16(ha1, LDB(0, 1, cc + 4), zs, 0, 0, 0);
            zs = __builtin_amdgcn_mfma_f32_16x16x32_bf16(pa0, LDB(1, 0, cc + 4), zs, 0, 0, 0);
            zs = __builtin_amdgcn_mfma_f32_16x16x32_bf16(pa1, LDB(1, 1, cc + 4), zs, 0, 0, 0);
            gin = __builtin_amdgcn_mfma_f32_16x16x32_bf16(ha0, LDB(0, 0, cc + 8), gin, 0, 0, 0);
            gin = __builtin_amdgcn_mfma_f32_16x16x32_bf16(ha1, LDB(0, 1, cc + 8), gin, 0, 0, 0);
            ghn = __builtin_amdgcn_mfma_f32_16x16x32_bf16(pa0, LDB(1, 0, cc + 8), ghn, 0, 0, 0);
            ghn = __builtin_amdgcn_mfma_f32_16x16x32_bf16(pa1, LDB(1, 1, cc + 8), ghn, 0, 0, 0);
#undef LDB
#pragma unroll
            for (int rg = 0; rg < 4; ++rg) {
                int row = row0 + quad * 4 + rg;
                float pv = h_prev[(size_t)row * 64 + cc * 16 + l16];
                float rr = fast_sigmoid(rs[rg]);
                float zz = fast_sigmoid(zs[rg]);
                float nn = fast_tanh(gin[rg] + rr * ghn[rg]);
                float hn = (1.f - zz) * nn + zz * pv;
                out_h[(size_t)row * 64 + cc * 16 + l16] = hn;
                p[rg][0] += hn * wv[cc][0];
                p[rg][1] += hn * wv[cc][1];
                p[rg][2] += hn * wv[cc][2];
            }
        }
#pragma unroll
        for (int rg = 0; rg < 4; ++rg) {
#pragma unroll
            for (int m = 1; m < 16; m <<= 1) {
                p[rg][0] += __shfl_xor(p[rg][0], m);
                p[rg][1] += __shfl_xor(p[rg][1], m);
                p[rg][2] += __shfl_xor(p[rg][2], m);
            }
        }
        if (l16 == 0) {
#pragma unroll
            for (int rg = 0; rg < 4; ++rg) {
                int row = row0 + quad * 4 + rg;
                out_o[(size_t)row * 3 + 0] = p[rg][0] + bro0;
                out_o[(size_t)row * 3 + 1] = p[rg][1] + bro1;
                out_o[(size_t)row * 3 + 2] = p[rg][2] + bro2;
            }
        }
    }
}

extern "C" void kernel_launch(void* const* d_in, const int* in_sizes, int n_in,
                              void* d_out, int out_size, void* d_ws, size_t ws_size,
                              hipStream_t stream) {
    const float* x        = (const float*)d_in[0];
    const float* h_prev   = (const float*)d_in[1];
    const int* node_idx   = (const int*)d_in[2];
    const int* hedge_idx  = (const int*)d_in[3];
    const int* edge_attr  = (const int*)d_in[4];
    const float* W_conv   = (const float*)d_in[5];
    const float* b_conv   = (const float*)d_in[6];
    const float* W_mix    = (const float*)d_in[7];
    const float* b_mix    = (const float*)d_in[8];
    const float* W_ih     = (const float*)d_in[9];
    const float* W_hh     = (const float*)d_in[10];
    const float* b_ih     = (const float*)d_in[11];
    const float* b_hh     = (const float*)d_in[12];
    const float* W_ro     = (const float*)d_in[13];
    const float* b_ro     = (const float*)d_in[14];

    char* p = (char*)d_ws;
    auto alloc = [&](size_t bytes) {
        char* r = p;
        p += (bytes + 63) & ~(size_t)63;
        return r;
    };
    // Region A: scan scratch (cnt/off/cursor/bsum, dead after k_scatter)
    // overlaid by agg16 (written in k_no2). 25.6MB >= 23.05MB scan need.
    char* regA     = alloc((size_t)2 * N_NODES * 64 * 2);
    int* cnt       = (int*)regA;
    int* off       = cnt + TOT;
    int* cursor    = off + TOT + 1;
    int* bsum      = cursor + TOT;
    bf16* agg16    = (bf16*)regA;
    int* offT      = (int*)alloc((size_t)(MSEG + 1) * NSUB * 4);
    int* sortedAll = (int*)alloc((size_t)2 * N_EDGES * 4);
    bf16* xb       = (bf16*)alloc((size_t)N_NODES * 64 * 2);
    bf16* ef16     = (bf16*)alloc((size_t)HSEG * 64 * 2);
    bf16* hbuf16   = (bf16*)alloc((size_t)N_NODES * 64 * 2);
    bf16* gru_pk   = (bf16*)alloc((size_t)GRU_PK * 2);
    bf16* mixf_pk  = (bf16*)alloc((size_t)MIX_PK * 2);
    float* bfused  = (float*)alloc(64 * 4);

    hipMemsetAsync(cnt, 0, (size_t)TOT * 4, stream);

    float* out_h = (float*)d_out;
    float* out_o = out_h + (size_t)N_NODES * 64;

    k_pack<<<16, 256, 0, stream>>>(W_conv, W_mix, b_conv, b_mix, W_ih, W_hh,
                                   gru_pk, mixf_pk, bfused);
    k_cast<<<(N_NODES * 64 / 8 + 255) / 256, 256, 0, stream>>>(x, xb);
    k_hist<<<(N_EDGES + 255) / 256, 256, 0, stream>>>(node_idx, hedge_idx, edge_attr, cnt);
    k_scan1<<<SCAN_BLOCKS, 256, 0, stream>>>(cnt, off, bsum);
    k_scan2<<<1, 1024, 0, stream>>>(bsum);
    k_scan3<<<SCAN_BLOCKS, 256, 0, stream>>>(off, bsum, cursor, offT);
    k_scatter<<<(N_EDGES + 255) / 256, 256, 0, stream>>>(node_idx, hedge_idx, edge_attr,
                                                         cursor, sortedAll);
    k_ef2<<<HSEG / 16, 256, 0, stream>>>(offT, sortedAll, xb, ef16);
    k_no2<<<NSEG / 16, 256, 0, stream>>>(offT, sortedAll, ef16, agg16);
    k_mix<<<512, 256, 0, stream>>>(agg16, mixf_pk, bfused, hbuf16);
    k_gru<<<768, 256, 0, stream>>>(gru_pk, hbuf16, h_prev, b_ih, b_hh,
                                   W_ro, b_ro, out_h, out_o);
}

// Round 3
// 402.806 us; speedup vs baseline: 1.3970x; 1.1476x over previous
//
#include <hip/hip_runtime.h>
#include <hip/hip_bf16.h>

#define N_NODES 100000
#define N_HEDGES 20000
#define N_EDGES 800000
#define HSEG (2 * N_HEDGES)            // 40000 hedge segments (t,h)
#define NSEG (2 * N_NODES)             // 200000 node segments (t,n)
#define MSEG (HSEG + NSEG)             // 240000 segments
#define NSUB 8                          // XCD-private sub-lists (blockIdx&7)
#define TOT (NSUB * MSEG)               // 1,920,000 counters
#define SCAN_BLOCKS ((TOT + 2047) / 2048)  // 938

#define MIX_PK  (4 * 4 * 64 * 8)        // 8192 packed bf16 fused-mix weights
#define GRU_PK  (2 * 2 * 12 * 64 * 8)   // 24576 for k_gru

typedef __hip_bfloat16 bf16;
typedef __attribute__((ext_vector_type(8))) short bf16x8;
typedef __attribute__((ext_vector_type(4))) float f32x4;

__device__ __forceinline__ float b2f(bf16 v) { return __bfloat162float(v); }
__device__ __forceinline__ bf16 f2b(float v) { return __float2bfloat16(v); }
__device__ __forceinline__ short f2s(float v) {
    bf16 b = __float2bfloat16(v);
    return *reinterpret_cast<short*>(&b);
}
__device__ __forceinline__ bf16x8 pack8(float4 a, float4 b) {
    bf16x8 r = {f2s(a.x), f2s(a.y), f2s(a.z), f2s(a.w),
                f2s(b.x), f2s(b.y), f2s(b.z), f2s(b.w)};
    return r;
}
__device__ __forceinline__ float fast_sigmoid(float x) {
    return __builtin_amdgcn_rcpf(1.f + __expf(-x));
}
__device__ __forceinline__ float fast_tanh(float x) {
    return 1.f - 2.f * __builtin_amdgcn_rcpf(1.f + __expf(2.f * x));
}

// ---------------------------------------------------------------------------
// Pack GRU weights into LDS layout; compute FUSED mix weights on device:
//   Wf[t] = W_conv[t] @ W_mix[t*64:(t+1)*64, :]   (64x64 each, f32 dot, bf16)
//   bfused = b_mix + sum_t b_conv[t] @ W_mix_t
// ---------------------------------------------------------------------------
__global__ __launch_bounds__(256) void k_pack(const float* __restrict__ Wc,
                                              const float* __restrict__ Wm,
                                              const float* __restrict__ bc,
                                              const float* __restrict__ bm,
                                              const float* __restrict__ Wih,
                                              const float* __restrict__ Whh,
                                              bf16* __restrict__ gru_pk,
                                              bf16* __restrict__ mixf_pk,
                                              float* __restrict__ bfused) {
    int idx = blockIdx.x * 256 + threadIdx.x;
    int stride = gridDim.x * 256;
    for (int i = idx; i < GRU_PK; i += stride) {
        int j = i & 7;
        int r = i >> 3;
        int ln = r & 63;
        int r2 = r >> 6;
        int ct = r2 % 12;
        int r3 = r2 / 12;
        int kt = r3 & 1;
        int mat = r3 >> 1;
        int k = kt * 32 + ((ln >> 4) << 3) + j;
        int n = ct * 16 + (ln & 15);
        float v = mat == 0 ? Wih[k * 192 + n] : Whh[k * 192 + n];
        gru_pk[i] = f2b(v);
    }
    for (int i = idx; i < MIX_PK; i += stride) {
        int j = i & 7, ln = (i >> 3) & 63, r2 = i >> 9;
        int ct = r2 & 3, kt = r2 >> 2;
        int k = kt * 32 + ((ln >> 4) << 3) + j;   // 0..127 (concat dim)
        int n = ct * 16 + (ln & 15);
        int t = k >> 6, kk = k & 63;
        float s = 0.f;
        for (int q = 0; q < 64; ++q)
            s += Wc[((size_t)t * 64 + kk) * 64 + q] * Wm[(size_t)(t * 64 + q) * 64 + n];
        mixf_pk[i] = f2b(s);
    }
    for (int i = idx; i < 64; i += stride) {
        float s = bm[i];
        for (int q = 0; q < 64; ++q)
            s += bc[q] * Wm[(size_t)q * 64 + i] + bc[64 + q] * Wm[(size_t)(64 + q) * 64 + i];
        bfused[i] = s;
    }
}

// ---------------------------------------------------------------------------
// Cast x to bf16 once; gathers then read 128B rows shared by both types.
// ---------------------------------------------------------------------------
__global__ __launch_bounds__(256) void k_cast(const float* __restrict__ x,
                                              bf16* __restrict__ xb) {
    size_t i = ((size_t)blockIdx.x * 256 + threadIdx.x) * 8;
    const float* xp = x + i;
    float4 a = *(const float4*)xp;
    float4 b = *(const float4*)(xp + 4);
    *(bf16x8*)(xb + i) = pack8(a, b);
}

// ---------------------------------------------------------------------------
// Histogram into XCD-private counters cnt[sub][seg], sub = blockIdx&7.
// NEW: the atomicAdd return value IS the edge's rank within (sub,seg) —
// record it (coalesced 4B stores) so k_scatter needs NO atomics at all.
// ---------------------------------------------------------------------------
__global__ __launch_bounds__(256) void k_hist(const int* __restrict__ node_idx,
                                              const int* __restrict__ hedge_idx,
                                              const int* __restrict__ attr,
                                              int* __restrict__ cnt,
                                              int* __restrict__ r1,
                                              int* __restrict__ r2) {
    int e = blockIdx.x * 256 + threadIdx.x;
    int base = (blockIdx.x & (NSUB - 1)) * MSEG;
    if (e < N_EDGES) {
        int t = attr[e];
        r1[e] = atomicAdd(&cnt[base + t * N_HEDGES + hedge_idx[e]], 1);
        r2[e] = atomicAdd(&cnt[base + HSEG + t * N_NODES + node_idx[e]], 1);
    }
}

// ---------------------------------------------------------------------------
// Scan 1/3: 2048 elems/block (256 thr x 8), partial exclusive scan + bsum.
// ---------------------------------------------------------------------------
__global__ __launch_bounds__(256) void k_scan1(const int* __restrict__ cnt,
                                               int* __restrict__ off,
                                               int* __restrict__ bsum) {
    __shared__ int s[256];
    int base = blockIdx.x * 2048 + threadIdx.x * 8;
    int v[8];
    int tsum = 0;
#pragma unroll
    for (int j = 0; j < 8; ++j) {
        int g = base + j;
        v[j] = (g < TOT) ? cnt[g] : 0;
        tsum += v[j];
    }
    s[threadIdx.x] = tsum;
    __syncthreads();
    for (int o = 1; o < 256; o <<= 1) {
        int t = (threadIdx.x >= o) ? s[threadIdx.x - o] : 0;
        __syncthreads();
        s[threadIdx.x] += t;
        __syncthreads();
    }
    int run = s[threadIdx.x] - tsum;
#pragma unroll
    for (int j = 0; j < 8; ++j) {
        int g = base + j;
        if (g < TOT) off[g] = run;
        run += v[j];
    }
    if (threadIdx.x == 255) bsum[blockIdx.x] = s[255];
}

// ---------------------------------------------------------------------------
// Scan 2/3: exclusive scan of SCAN_BLOCKS (<=1024) block sums, one block.
// ---------------------------------------------------------------------------
__global__ __launch_bounds__(1024) void k_scan2(int* __restrict__ bsum) {
    __shared__ int s[1024];
    int tid = threadIdx.x;
    int v = (tid < SCAN_BLOCKS) ? bsum[tid] : 0;
    s[tid] = v;
    __syncthreads();
    for (int o = 1; o < 1024; o <<= 1) {
        int t = (tid >= o) ? s[tid - o] : 0;
        __syncthreads();
        s[tid] += t;
        __syncthreads();
    }
    if (tid < SCAN_BLOCKS) bsum[tid] = s[tid] - v;
}

// ---------------------------------------------------------------------------
// Scan 3/3: final off + TRANSPOSED offsets offT[seg][8]. (cursor array is
// gone — scatter uses off + recorded ranks.)
// Sentinel row offT[MSEG][k] = off[(k+1)*MSEG].
// ---------------------------------------------------------------------------
__global__ __launch_bounds__(256) void k_scan3(int* __restrict__ off,
                                               const int* __restrict__ bsum,
                                               int* __restrict__ offT) {
    int base = blockIdx.x * 2048 + threadIdx.x * 8;
    int add = bsum[blockIdx.x];
#pragma unroll
    for (int j = 0; j < 8; ++j) {
        int g = base + j;
        if (g < TOT) {
            int v = off[g] + add;
            off[g] = v;
            int k = g / MSEG, s = g - k * MSEG;
            offT[s * NSUB + k] = v;
            if (s == 0 && k > 0) offT[MSEG * NSUB + (k - 1)] = v;  // end of sub k-1
        }
    }
    if (base == 0) offT[MSEG * NSUB + 7] = 2 * N_EDGES;
}

// ---------------------------------------------------------------------------
// Scatter into XCD-private sub-lists (sub = blockIdx&7). ATOMIC-FREE:
// position = off[seg] + rank recorded by k_hist. Pure loads + stores.
// ---------------------------------------------------------------------------
__global__ __launch_bounds__(256) void k_scatter(const int* __restrict__ node_idx,
                                                 const int* __restrict__ hedge_idx,
                                                 const int* __restrict__ attr,
                                                 const int* __restrict__ off,
                                                 const int* __restrict__ r1,
                                                 const int* __restrict__ r2,
                                                 int* __restrict__ sortedAll) {
    int e = blockIdx.x * 256 + threadIdx.x;
    int base = (blockIdx.x & (NSUB - 1)) * MSEG;
    if (e < N_EDGES) {
        int t = attr[e], n = node_idx[e], h = hedge_idx[e];
        int p1 = off[base + t * N_HEDGES + h] + r1[e];
        sortedAll[p1] = n;
        int p2 = off[base + HSEG + t * N_NODES + n] + r2[e];
        sortedAll[p2] = t * N_HEDGES + h;
    }
}

// ---------------------------------------------------------------------------
// Quarter-per-segment gather: each 16-lane quarter owns one segment (4 per
// wave). One coalesced load ov = offT[seg0*8 + lane] provides all 4 quarters'
// 8 begs + 8 ends. Uniform k-loop with per-quarter exact bounds via shfl.
// 16 lanes x 8B = one 128B row per quarter per iter. Epilogue: one coalesced
// 512B store per wave, no cross-lane reduction.
// ---------------------------------------------------------------------------
__device__ __forceinline__ void seg_quarter(const int* __restrict__ offT,
                                            const int* __restrict__ sortedAll,
                                            const bf16* __restrict__ rows,
                                            int seg0, int lane,
                                            float acc[4], int* total) {
    int q = lane >> 4, l16 = lane & 15;
    int ov = offT[(size_t)seg0 * NSUB + lane];  // begs+ends for 4 quarters
    acc[0] = acc[1] = acc[2] = acc[3] = 0.f;
    int tot = 0;
#pragma unroll
    for (int k = 0; k < NSUB; ++k) {
        int myb = __shfl(ov, q * NSUB + k);
        int mye = __shfl(ov, q * NSUB + k + NSUB);
        tot += mye - myb;
        for (int i = myb; i < mye; ++i) {
            int idx = sortedAll[i];  // 16 lanes same addr (broadcast)
            uint2 v = *(const uint2*)(rows + (size_t)idx * 64 + l16 * 4);
            acc[0] += __uint_as_float(v.x << 16);
            acc[1] += __uint_as_float(v.x & 0xffff0000u);
            acc[2] += __uint_as_float(v.y << 16);
            acc[3] += __uint_as_float(v.y & 0xffff0000u);
        }
    }
    *total = tot;
}

// CSR node->hedge: ef_raw[t][h] = (1/B) * sum xb rows (RAW x, no weights).
__global__ __launch_bounds__(256) void k_ef2(const int* __restrict__ offT,
                                             const int* __restrict__ sortedAll,
                                             const bf16* __restrict__ xb,
                                             bf16* __restrict__ ef16) {
    int wid = threadIdx.x >> 6, lane = threadIdx.x & 63;
    int seg0 = (blockIdx.x * 4 + wid) * 4;
    if (seg0 >= HSEG) return;
    float acc[4];
    int tot;
    seg_quarter(offT, sortedAll, xb, seg0, lane, acc, &tot);
    float scale = tot > 0 ? 1.0f / (float)tot : 0.f;
    int s = seg0 + (lane >> 4), l16 = lane & 15;
    uint lo = (uint)(unsigned short)f2s(acc[0] * scale) |
              ((uint)(unsigned short)f2s(acc[1] * scale) << 16);
    uint hi = (uint)(unsigned short)f2s(acc[2] * scale) |
              ((uint)(unsigned short)f2s(acc[3] * scale) << 16);
    *(uint2*)(ef16 + (size_t)s * 64 + l16 * 4) = make_uint2(lo, hi);
}

// CSR hedge->node: agg[t][n] = (1/D) * sum ef_raw rows. Bias folded into
// bfused (k_mix), so no add here.
__global__ __launch_bounds__(256) void k_no2(const int* __restrict__ offT,
                                             const int* __restrict__ sortedAll,
                                             const bf16* __restrict__ ef16,
                                             bf16* __restrict__ agg16) {
    int wid = threadIdx.x >> 6, lane = threadIdx.x & 63;
    int j0 = (blockIdx.x * 4 + wid) * 4;
    if (j0 >= NSEG) return;
    float acc[4];
    int tot;
    seg_quarter(offT, sortedAll, ef16, HSEG + j0, lane, acc, &tot);
    float scale = tot > 0 ? 1.0f / (float)tot : 0.f;
    int q = lane >> 4, l16 = lane & 15;
    int j = j0 + q;
    uint lo = (uint)(unsigned short)f2s(acc[0] * scale) |
              ((uint)(unsigned short)f2s(acc[1] * scale) << 16);
    uint hi = (uint)(unsigned short)f2s(acc[2] * scale) |
              ((uint)(unsigned short)f2s(acc[3] * scale) << 16);
    *(uint2*)(agg16 + (size_t)j * 64 + l16 * 4) = make_uint2(lo, hi);
}

// ---------------------------------------------------------------------------
// MFMA mix (fused): h = relu([agg0|agg1] @ Wf + bfused), K=128 (4 k-frags).
// ---------------------------------------------------------------------------
__global__ __launch_bounds__(256) void k_mix(const bf16* __restrict__ agg16,
                                             const bf16* __restrict__ mixf_pk,
                                             const float* __restrict__ bfused,
                                             bf16* __restrict__ hbuf16) {
    __shared__ __align__(16) bf16 Wpk[MIX_PK];  // 16 KB
    {
        const bf16x8* src = (const bf16x8*)mixf_pk;
        bf16x8* dst = (bf16x8*)Wpk;
        for (int i = threadIdx.x; i < MIX_PK / 8; i += 256) dst[i] = src[i];
    }
    __syncthreads();
    int wid = threadIdx.x >> 6, lane = threadIdx.x & 63;
    int quad = lane >> 4, l16 = lane & 15;
    float bmv[4];
#pragma unroll
    for (int ct = 0; ct < 4; ++ct) bmv[ct] = bfused[ct * 16 + l16];

    int wave = blockIdx.x * 4 + wid, n_waves = gridDim.x * 4;
    for (int tile = wave; tile < N_NODES / 16; tile += n_waves) {
        int row0 = tile * 16;
        int arow = row0 + l16;
        bf16x8 af[4];
#pragma unroll
        for (int kt = 0; kt < 4; ++kt) {
            const bf16* src = (kt < 2)
                ? agg16 + (size_t)arow * 64 + kt * 32 + quad * 8
                : agg16 + ((size_t)N_NODES + arow) * 64 + (kt - 2) * 32 + quad * 8;
            af[kt] = *(const bf16x8*)src;
        }
#define LDBM(kt, ct) (*(const bf16x8*)&Wpk[(((kt)*4 + (ct)) * 64 + lane) * 8])
#pragma unroll
        for (int ct = 0; ct < 4; ++ct) {
            f32x4 acc = {bmv[ct], bmv[ct], bmv[ct], bmv[ct]};
#pragma unroll
            for (int kt = 0; kt < 4; ++kt)
                acc = __builtin_amdgcn_mfma_f32_16x16x32_bf16(af[kt], LDBM(kt, ct), acc, 0, 0, 0);
#pragma unroll
            for (int rg = 0; rg < 4; ++rg) {
                int row = row0 + quad * 4 + rg;
                hbuf16[(size_t)row * 64 + ct * 16 + l16] = f2b(fmaxf(acc[rg], 0.f));
            }
        }
#undef LDBM
    }
}

// ---------------------------------------------------------------------------
// MFMA GRU. Gate fusion: r = sigmoid(gi_r + gh_r) -> ONE accumulator chain of
// 4 MFMAs; same for z. Only the n gate needs separate gi_n / gh_n. Biases in
// MFMA C-init; fast sigmoid/tanh via v_exp+v_rcp.
// ---------------------------------------------------------------------------
#define GRU_TILES (N_NODES / 16)
__global__ __launch_bounds__(256) void k_gru(const bf16* __restrict__ gru_pk,
                                             const bf16* __restrict__ hbuf16,
                                             const float* __restrict__ h_prev,
                                             const float* __restrict__ bih_g,
                                             const float* __restrict__ bhh_g,
                                             const float* __restrict__ Wro_g,
                                             const float* __restrict__ bro_g,
                                             float* __restrict__ out_h,
                                             float* __restrict__ out_o) {
    __shared__ __align__(16) bf16 Wpk[GRU_PK];  // 48 KB
    {
        const bf16x8* src = (const bf16x8*)gru_pk;
        bf16x8* dst = (bf16x8*)Wpk;
        for (int i = threadIdx.x; i < GRU_PK / 8; i += 256) dst[i] = src[i];
    }
    __syncthreads();

    int wid = threadIdx.x >> 6, lane = threadIdx.x & 63;
    int quad = lane >> 4, l16 = lane & 15;

    float br_c[4], bz_c[4], bin_c[4], bhn_c[4], wv[4][3];
#pragma unroll
    for (int cc = 0; cc < 4; ++cc) {
        int col = cc * 16 + l16;
        br_c[cc] = bih_g[col] + bhh_g[col];
        bz_c[cc] = bih_g[64 + col] + bhh_g[64 + col];
        bin_c[cc] = bih_g[128 + col];
        bhn_c[cc] = bhh_g[128 + col];
        wv[cc][0] = Wro_g[col * 64 + 0];
        wv[cc][1] = Wro_g[col * 64 + 1];
        wv[cc][2] = Wro_g[col * 64 + 2];
    }
    float bro0 = bro_g[0], bro1 = bro_g[1], bro2 = bro_g[2];

    int wave = blockIdx.x * 4 + wid;
    int n_waves = gridDim.x * 4;

    for (int tile = wave; tile < GRU_TILES; tile += n_waves) {
        int row0 = tile * 16;
        const bf16* ha_p = hbuf16 + (size_t)(row0 + l16) * 64 + quad * 8;
        bf16x8 ha0 = *(const bf16x8*)ha_p;
        bf16x8 ha1 = *(const bf16x8*)(ha_p + 32);
        const float* pp = h_prev + (size_t)(row0 + l16) * 64 + quad * 8;
        bf16x8 pa0 = pack8(*(const float4*)pp, *(const float4*)(pp + 4));
        bf16x8 pa1 = pack8(*(const float4*)(pp + 32), *(const float4*)(pp + 36));

        float p[4][3];
#pragma unroll
        for (int rg = 0; rg < 4; ++rg) p[rg][0] = p[rg][1] = p[rg][2] = 0.f;

#pragma unroll
        for (int cc = 0; cc < 4; ++cc) {
#define LDB(mat, kt, ct) (*(const bf16x8*)&Wpk[((((mat)*2 + (kt)) * 12 + (ct)) * 64 + lane) * 8])
            f32x4 rs = {br_c[cc], br_c[cc], br_c[cc], br_c[cc]};
            f32x4 zs = {bz_c[cc], bz_c[cc], bz_c[cc], bz_c[cc]};
            f32x4 gin = {bin_c[cc], bin_c[cc], bin_c[cc], bin_c[cc]};
            f32x4 ghn = {bhn_c[cc], bhn_c[cc], bhn_c[cc], bhn_c[cc]};
            rs = __builtin_amdgcn_mfma_f32_16x16x32_bf16(ha0, LDB(0, 0, cc), rs, 0, 0, 0);
            rs = __builtin_amdgcn_mfma_f32_16x16x32_bf16(ha1, LDB(0, 1, cc), rs, 0, 0, 0);
            rs = __builtin_amdgcn_mfma_f32_16x16x32_bf16(pa0, LDB(1, 0, cc), rs, 0, 0, 0);
            rs = __builtin_amdgcn_mfma_f32_16x16x32_bf16(pa1, LDB(1, 1, cc), rs, 0, 0, 0);
            zs = __builtin_amdgcn_mfma_f32_16x16x32_bf16(ha0, LDB(0, 0, cc + 4), zs, 0, 0, 0);
            zs = __builtin_amdgcn_mfma_f32_16x16x32_bf16(ha1, LDB(0, 1, cc + 4), zs, 0, 0, 0);
            zs = __builtin_amdgcn_mfma_f32_16x16x32_bf16(pa0, LDB(1, 0, cc + 4), zs, 0, 0, 0);
            zs = __builtin_amdgcn_mfma_f32_16x16x32_bf16(pa1, LDB(1, 1, cc + 4), zs, 0, 0, 0);
            gin = __builtin_amdgcn_mfma_f32_16x16x32_bf16(ha0, LDB(0, 0, cc + 8), gin, 0, 0, 0);
            gin = __builtin_amdgcn_mfma_f32_16x16x32_bf16(ha1, LDB(0, 1, cc + 8), gin, 0, 0, 0);
            ghn = __builtin_amdgcn_mfma_f32_16x16x32_bf16(pa0, LDB(1, 0, cc + 8), ghn, 0, 0, 0);
            ghn = __builtin_amdgcn_mfma_f32_16x16x32_bf16(pa1, LDB(1, 1, cc + 8), ghn, 0, 0, 0);
#undef LDB
#pragma unroll
            for (int rg = 0; rg < 4; ++rg) {
                int row = row0 + quad * 4 + rg;
                float pv = h_prev[(size_t)row * 64 + cc * 16 + l16];
                float rr = fast_sigmoid(rs[rg]);
                float zz = fast_sigmoid(zs[rg]);
                float nn = fast_tanh(gin[rg] + rr * ghn[rg]);
                float hn = (1.f - zz) * nn + zz * pv;
                out_h[(size_t)row * 64 + cc * 16 + l16] = hn;
                p[rg][0] += hn * wv[cc][0];
                p[rg][1] += hn * wv[cc][1];
                p[rg][2] += hn * wv[cc][2];
            }
        }
#pragma unroll
        for (int rg = 0; rg < 4; ++rg) {
#pragma unroll
            for (int m = 1; m < 16; m <<= 1) {
                p[rg][0] += __shfl_xor(p[rg][0], m);
                p[rg][1] += __shfl_xor(p[rg][1], m);
                p[rg][2] += __shfl_xor(p[rg][2], m);
            }
        }
        if (l16 == 0) {
#pragma unroll
            for (int rg = 0; rg < 4; ++rg) {
                int row = row0 + quad * 4 + rg;
                out_o[(size_t)row * 3 + 0] = p[rg][0] + bro0;
                out_o[(size_t)row * 3 + 1] = p[rg][1] + bro1;
                out_o[(size_t)row * 3 + 2] = p[rg][2] + bro2;
            }
        }
    }
}

extern "C" void kernel_launch(void* const* d_in, const int* in_sizes, int n_in,
                              void* d_out, int out_size, void* d_ws, size_t ws_size,
                              hipStream_t stream) {
    const float* x        = (const float*)d_in[0];
    const float* h_prev   = (const float*)d_in[1];
    const int* node_idx   = (const int*)d_in[2];
    const int* hedge_idx  = (const int*)d_in[3];
    const int* edge_attr  = (const int*)d_in[4];
    const float* W_conv   = (const float*)d_in[5];
    const float* b_conv   = (const float*)d_in[6];
    const float* W_mix    = (const float*)d_in[7];
    const float* b_mix    = (const float*)d_in[8];
    const float* W_ih     = (const float*)d_in[9];
    const float* W_hh     = (const float*)d_in[10];
    const float* b_ih     = (const float*)d_in[11];
    const float* b_hh     = (const float*)d_in[12];
    const float* W_ro     = (const float*)d_in[13];
    const float* b_ro     = (const float*)d_in[14];

    char* p = (char*)d_ws;
    auto alloc = [&](size_t bytes) {
        char* r = p;
        p += (bytes + 63) & ~(size_t)63;
        return r;
    };
    // Region A: scan scratch (cnt/off/bsum, dead after k_scatter) overlaid
    // by agg16 (written in k_no2). 25.6MB >= 15.4MB scan need.
    char* regA     = alloc((size_t)2 * N_NODES * 64 * 2);
    int* cnt       = (int*)regA;
    int* off       = cnt + TOT;
    int* bsum      = off + TOT + 1;
    bf16* agg16    = (bf16*)regA;
    int* offT      = (int*)alloc((size_t)(MSEG + 1) * NSUB * 4);
    int* sortedAll = (int*)alloc((size_t)2 * N_EDGES * 4);
    int* r1        = (int*)alloc((size_t)N_EDGES * 4);
    int* r2        = (int*)alloc((size_t)N_EDGES * 4);
    bf16* xb       = (bf16*)alloc((size_t)N_NODES * 64 * 2);
    bf16* ef16     = (bf16*)alloc((size_t)HSEG * 64 * 2);
    bf16* hbuf16   = (bf16*)alloc((size_t)N_NODES * 64 * 2);
    bf16* gru_pk   = (bf16*)alloc((size_t)GRU_PK * 2);
    bf16* mixf_pk  = (bf16*)alloc((size_t)MIX_PK * 2);
    float* bfused  = (float*)alloc(64 * 4);

    hipMemsetAsync(cnt, 0, (size_t)TOT * 4, stream);

    float* out_h = (float*)d_out;
    float* out_o = out_h + (size_t)N_NODES * 64;

    k_pack<<<16, 256, 0, stream>>>(W_conv, W_mix, b_conv, b_mix, W_ih, W_hh,
                                   gru_pk, mixf_pk, bfused);
    k_cast<<<(N_NODES * 64 / 8 + 255) / 256, 256, 0, stream>>>(x, xb);
    k_hist<<<(N_EDGES + 255) / 256, 256, 0, stream>>>(node_idx, hedge_idx, edge_attr,
                                                      cnt, r1, r2);
    k_scan1<<<SCAN_BLOCKS, 256, 0, stream>>>(cnt, off, bsum);
    k_scan2<<<1, 1024, 0, stream>>>(bsum);
    k_scan3<<<SCAN_BLOCKS, 256, 0, stream>>>(off, bsum, offT);
    k_scatter<<<(N_EDGES + 255) / 256, 256, 0, stream>>>(node_idx, hedge_idx, edge_attr,
                                                         off, r1, r2, sortedAll);
    k_ef2<<<HSEG / 16, 256, 0, stream>>>(offT, sortedAll, xb, ef16);
    k_no2<<<NSEG / 16, 256, 0, stream>>>(offT, sortedAll, ef16, agg16);
    k_mix<<<512, 256, 0, stream>>>(agg16, mixf_pk, bfused, hbuf16);
    k_gru<<<768, 256, 0, stream>>>(gru_pk, hbuf16, h_prev, b_ih, b_hh,
                                   W_ro, b_ro, out_h, out_o);
}

// Round 4
// 396.587 us; speedup vs baseline: 1.4189x; 1.0157x over previous
//
#include <hip/hip_runtime.h>
#include <hip/hip_bf16.h>

#define N_NODES 100000
#define N_HEDGES 20000
#define N_EDGES 800000
#define HSEG (2 * N_HEDGES)            // 40000 hedge segments (t,h)
#define NSEG (2 * N_NODES)             // 200000 node segments (t,n)
#define MSEG (HSEG + NSEG)             // 240000 segments
#define NSUB 8                          // XCD-private sub-lists (per edge: (e>>8)&7)
#define TOT (NSUB * MSEG)               // 1,920,000 counters
#define SCAN_BLOCKS ((TOT + 2047) / 2048)  // 938
#define HIST_THREADS (((N_EDGES / 2 + 255) / 256) * 256)  // 400128

#define MIX_PK  (4 * 4 * 64 * 8)        // 8192 packed bf16 fused-mix weights
#define GRU_PK  (2 * 2 * 12 * 64 * 8)   // 24576 for k_gru

typedef __hip_bfloat16 bf16;
typedef __attribute__((ext_vector_type(8))) short bf16x8;
typedef __attribute__((ext_vector_type(4))) float f32x4;

__device__ __forceinline__ float b2f(bf16 v) { return __bfloat162float(v); }
__device__ __forceinline__ bf16 f2b(float v) { return __float2bfloat16(v); }
__device__ __forceinline__ short f2s(float v) {
    bf16 b = __float2bfloat16(v);
    return *reinterpret_cast<short*>(&b);
}
__device__ __forceinline__ bf16x8 pack8(float4 a, float4 b) {
    bf16x8 r = {f2s(a.x), f2s(a.y), f2s(a.z), f2s(a.w),
                f2s(b.x), f2s(b.y), f2s(b.z), f2s(b.w)};
    return r;
}
__device__ __forceinline__ float fast_sigmoid(float x) {
    return __builtin_amdgcn_rcpf(1.f + __expf(-x));
}
__device__ __forceinline__ float fast_tanh(float x) {
    return 1.f - 2.f * __builtin_amdgcn_rcpf(1.f + __expf(2.f * x));
}

// ---------------------------------------------------------------------------
// Pack GRU weights into LDS layout; compute FUSED mix weights on device:
//   Wf[t] = W_conv[t] @ W_mix[t*64:(t+1)*64, :]   (64x64 each, f32 dot, bf16)
//   bfused = b_mix + sum_t b_conv[t] @ W_mix_t
// ---------------------------------------------------------------------------
__global__ __launch_bounds__(256) void k_pack(const float* __restrict__ Wc,
                                              const float* __restrict__ Wm,
                                              const float* __restrict__ bc,
                                              const float* __restrict__ bm,
                                              const float* __restrict__ Wih,
                                              const float* __restrict__ Whh,
                                              bf16* __restrict__ gru_pk,
                                              bf16* __restrict__ mixf_pk,
                                              float* __restrict__ bfused) {
    int idx = blockIdx.x * 256 + threadIdx.x;
    int stride = gridDim.x * 256;
    for (int i = idx; i < GRU_PK; i += stride) {
        int j = i & 7;
        int r = i >> 3;
        int ln = r & 63;
        int r2 = r >> 6;
        int ct = r2 % 12;
        int r3 = r2 / 12;
        int kt = r3 & 1;
        int mat = r3 >> 1;
        int k = kt * 32 + ((ln >> 4) << 3) + j;
        int n = ct * 16 + (ln & 15);
        float v = mat == 0 ? Wih[k * 192 + n] : Whh[k * 192 + n];
        gru_pk[i] = f2b(v);
    }
    for (int i = idx; i < MIX_PK; i += stride) {
        int j = i & 7, ln = (i >> 3) & 63, r2 = i >> 9;
        int ct = r2 & 3, kt = r2 >> 2;
        int k = kt * 32 + ((ln >> 4) << 3) + j;   // 0..127 (concat dim)
        int n = ct * 16 + (ln & 15);
        int t = k >> 6, kk = k & 63;
        float s = 0.f;
        for (int q = 0; q < 64; ++q)
            s += Wc[((size_t)t * 64 + kk) * 64 + q] * Wm[(size_t)(t * 64 + q) * 64 + n];
        mixf_pk[i] = f2b(s);
    }
    for (int i = idx; i < 64; i += stride) {
        float s = bm[i];
        for (int q = 0; q < 64; ++q)
            s += bc[q] * Wm[(size_t)q * 64 + i] + bc[64 + q] * Wm[(size_t)(64 + q) * 64 + i];
        bfused[i] = s;
    }
}

// ---------------------------------------------------------------------------
// Cast x to bf16 once; gathers then read 128B rows shared by both types.
// ---------------------------------------------------------------------------
__global__ __launch_bounds__(256) void k_cast(const float* __restrict__ x,
                                              bf16* __restrict__ xb) {
    size_t i = ((size_t)blockIdx.x * 256 + threadIdx.x) * 8;
    const float* xp = x + i;
    float4 a = *(const float4*)xp;
    float4 b = *(const float4*)(xp + 4);
    *(bf16x8*)(xb + i) = pack8(a, b);
}

// ---------------------------------------------------------------------------
// Histogram into sub-private counters cnt[sub][seg], sub = (e>>8)&7 (same
// mapping as one-edge-per-thread blockIdx&7, kept consistent with k_scatter).
// The atomicAdd return IS the edge's rank within (sub,seg) — recorded so
// k_scatter needs no atomics. 2 edges/thread: 4 independent atomics in
// flight per lane (bound is transaction throughput; this removes any
// residual latency exposure).
// ---------------------------------------------------------------------------
__global__ __launch_bounds__(256) void k_hist(const int* __restrict__ node_idx,
                                              const int* __restrict__ hedge_idx,
                                              const int* __restrict__ attr,
                                              int* __restrict__ cnt,
                                              int* __restrict__ r1,
                                              int* __restrict__ r2) {
    int e1 = blockIdx.x * 256 + threadIdx.x;
    int e2 = e1 + HIST_THREADS;
    int t1 = 0, h1 = 0, n1 = 0, t2 = 0, h2 = 0, n2 = 0;
    if (e1 < N_EDGES) { t1 = attr[e1]; h1 = hedge_idx[e1]; n1 = node_idx[e1]; }
    if (e2 < N_EDGES) { t2 = attr[e2]; h2 = hedge_idx[e2]; n2 = node_idx[e2]; }
    if (e1 < N_EDGES) {
        int base = ((e1 >> 8) & (NSUB - 1)) * MSEG;
        r1[e1] = atomicAdd(&cnt[base + t1 * N_HEDGES + h1], 1);
        r2[e1] = atomicAdd(&cnt[base + HSEG + t1 * N_NODES + n1], 1);
    }
    if (e2 < N_EDGES) {
        int base = ((e2 >> 8) & (NSUB - 1)) * MSEG;
        r1[e2] = atomicAdd(&cnt[base + t2 * N_HEDGES + h2], 1);
        r2[e2] = atomicAdd(&cnt[base + HSEG + t2 * N_NODES + n2], 1);
    }
}

// ---------------------------------------------------------------------------
// Scan 1/3: 2048 elems/block (256 thr x 8), partial exclusive scan + bsum.
// ---------------------------------------------------------------------------
__global__ __launch_bounds__(256) void k_scan1(const int* __restrict__ cnt,
                                               int* __restrict__ off,
                                               int* __restrict__ bsum) {
    __shared__ int s[256];
    int base = blockIdx.x * 2048 + threadIdx.x * 8;
    int v[8];
    int tsum = 0;
#pragma unroll
    for (int j = 0; j < 8; ++j) {
        int g = base + j;
        v[j] = (g < TOT) ? cnt[g] : 0;
        tsum += v[j];
    }
    s[threadIdx.x] = tsum;
    __syncthreads();
    for (int o = 1; o < 256; o <<= 1) {
        int t = (threadIdx.x >= o) ? s[threadIdx.x - o] : 0;
        __syncthreads();
        s[threadIdx.x] += t;
        __syncthreads();
    }
    int run = s[threadIdx.x] - tsum;
#pragma unroll
    for (int j = 0; j < 8; ++j) {
        int g = base + j;
        if (g < TOT) off[g] = run;
        run += v[j];
    }
    if (threadIdx.x == 255) bsum[blockIdx.x] = s[255];
}

// ---------------------------------------------------------------------------
// Scan 2/3: exclusive scan of SCAN_BLOCKS (<=1024) block sums, one block.
// ---------------------------------------------------------------------------
__global__ __launch_bounds__(1024) void k_scan2(int* __restrict__ bsum) {
    __shared__ int s[1024];
    int tid = threadIdx.x;
    int v = (tid < SCAN_BLOCKS) ? bsum[tid] : 0;
    s[tid] = v;
    __syncthreads();
    for (int o = 1; o < 1024; o <<= 1) {
        int t = (tid >= o) ? s[tid - o] : 0;
        __syncthreads();
        s[tid] += t;
        __syncthreads();
    }
    if (tid < SCAN_BLOCKS) bsum[tid] = s[tid] - v;
}

// ---------------------------------------------------------------------------
// Scan 3/3: writes ONLY the transposed offsets offT[seg][8] (scatter and the
// gathers both read offT; the linear `off` final write is dropped).
// Sentinel row offT[MSEG][k] = off[(k+1)*MSEG].
// ---------------------------------------------------------------------------
__global__ __launch_bounds__(256) void k_scan3(const int* __restrict__ off,
                                               const int* __restrict__ bsum,
                                               int* __restrict__ offT) {
    int base = blockIdx.x * 2048 + threadIdx.x * 8;
    int add = bsum[blockIdx.x];
#pragma unroll
    for (int j = 0; j < 8; ++j) {
        int g = base + j;
        if (g < TOT) {
            int v = off[g] + add;
            int k = g / MSEG, s = g - k * MSEG;
            offT[s * NSUB + k] = v;
            if (s == 0 && k > 0) offT[MSEG * NSUB + (k - 1)] = v;  // end of sub k-1
        }
    }
    if (base == 0) offT[MSEG * NSUB + 7] = 2 * N_EDGES;
}

// ---------------------------------------------------------------------------
// Scatter into sub-private lists (sub = blockIdx&7 == (e>>8)&7). ATOMIC-FREE:
// position = offT[seg][sub] + rank recorded by k_hist. Pure loads + stores.
// ---------------------------------------------------------------------------
__global__ __launch_bounds__(256) void k_scatter(const int* __restrict__ node_idx,
                                                 const int* __restrict__ hedge_idx,
                                                 const int* __restrict__ attr,
                                                 const int* __restrict__ offT,
                                                 const int* __restrict__ r1,
                                                 const int* __restrict__ r2,
                                                 int* __restrict__ sortedAll) {
    int e = blockIdx.x * 256 + threadIdx.x;
    int sub = blockIdx.x & (NSUB - 1);
    if (e < N_EDGES) {
        int t = attr[e], n = node_idx[e], h = hedge_idx[e];
        int p1 = offT[(size_t)(t * N_HEDGES + h) * NSUB + sub] + r1[e];
        sortedAll[p1] = n;
        int p2 = offT[(size_t)(HSEG + t * N_NODES + n) * NSUB + sub] + r2[e];
        sortedAll[p2] = t * N_HEDGES + h;
    }
}

// ---------------------------------------------------------------------------
// Quarter-per-segment gather: each 16-lane quarter owns one segment (4 per
// wave). One coalesced load ov = offT[seg0*8 + lane] provides all 4 quarters'
// 8 begs + 8 ends. Uniform k-loop with per-quarter exact bounds via shfl.
// 16 lanes x 8B = one 128B row per quarter per iter. Epilogue: one coalesced
// 512B store per wave, no cross-lane reduction.
// ---------------------------------------------------------------------------
__device__ __forceinline__ void seg_quarter(const int* __restrict__ offT,
                                            const int* __restrict__ sortedAll,
                                            const bf16* __restrict__ rows,
                                            int seg0, int lane,
                                            float acc[4], int* total) {
    int q = lane >> 4, l16 = lane & 15;
    int ov = offT[(size_t)seg0 * NSUB + lane];  // begs+ends for 4 quarters
    acc[0] = acc[1] = acc[2] = acc[3] = 0.f;
    int tot = 0;
#pragma unroll
    for (int k = 0; k < NSUB; ++k) {
        int myb = __shfl(ov, q * NSUB + k);
        int mye = __shfl(ov, q * NSUB + k + NSUB);
        tot += mye - myb;
        for (int i = myb; i < mye; ++i) {
            int idx = sortedAll[i];  // 16 lanes same addr (broadcast)
            uint2 v = *(const uint2*)(rows + (size_t)idx * 64 + l16 * 4);
            acc[0] += __uint_as_float(v.x << 16);
            acc[1] += __uint_as_float(v.x & 0xffff0000u);
            acc[2] += __uint_as_float(v.y << 16);
            acc[3] += __uint_as_float(v.y & 0xffff0000u);
        }
    }
    *total = tot;
}

// CSR node->hedge: ef_raw[t][h] = (1/B) * sum xb rows (RAW x, no weights).
__global__ __launch_bounds__(256) void k_ef2(const int* __restrict__ offT,
                                             const int* __restrict__ sortedAll,
                                             const bf16* __restrict__ xb,
                                             bf16* __restrict__ ef16) {
    int wid = threadIdx.x >> 6, lane = threadIdx.x & 63;
    int seg0 = (blockIdx.x * 4 + wid) * 4;
    if (seg0 >= HSEG) return;
    float acc[4];
    int tot;
    seg_quarter(offT, sortedAll, xb, seg0, lane, acc, &tot);
    float scale = tot > 0 ? 1.0f / (float)tot : 0.f;
    int s = seg0 + (lane >> 4), l16 = lane & 15;
    uint lo = (uint)(unsigned short)f2s(acc[0] * scale) |
              ((uint)(unsigned short)f2s(acc[1] * scale) << 16);
    uint hi = (uint)(unsigned short)f2s(acc[2] * scale) |
              ((uint)(unsigned short)f2s(acc[3] * scale) << 16);
    *(uint2*)(ef16 + (size_t)s * 64 + l16 * 4) = make_uint2(lo, hi);
}

// CSR hedge->node: agg[t][n] = (1/D) * sum ef_raw rows. Bias folded into
// bfused (k_mixgru), so no add here.
__global__ __launch_bounds__(256) void k_no2(const int* __restrict__ offT,
                                             const int* __restrict__ sortedAll,
                                             const bf16* __restrict__ ef16,
                                             bf16* __restrict__ agg16) {
    int wid = threadIdx.x >> 6, lane = threadIdx.x & 63;
    int j0 = (blockIdx.x * 4 + wid) * 4;
    if (j0 >= NSEG) return;
    float acc[4];
    int tot;
    seg_quarter(offT, sortedAll, ef16, HSEG + j0, lane, acc, &tot);
    float scale = tot > 0 ? 1.0f / (float)tot : 0.f;
    int q = lane >> 4, l16 = lane & 15;
    int j = j0 + q;
    uint lo = (uint)(unsigned short)f2s(acc[0] * scale) |
              ((uint)(unsigned short)f2s(acc[1] * scale) << 16);
    uint hi = (uint)(unsigned short)f2s(acc[2] * scale) |
              ((uint)(unsigned short)f2s(acc[3] * scale) << 16);
    *(uint2*)(agg16 + (size_t)j * 64 + l16 * 4) = make_uint2(lo, hi);
}

// ---------------------------------------------------------------------------
// FUSED mix+GRU. Per 16-row tile:
//   1) mix: acc = relu([agg0|agg1] @ Wf + bfused)  (MFMA, C/D layout)
//   2) bounce the 16x64 bf16 tile through a PER-WAVE 2KB LDS buffer to
//      re-layout D-fragment -> A-fragment (no __syncthreads: same-wave DS
//      ops execute in order). Chunk-XOR swizzle (chunk ^= row&7) makes the
//      b128 re-reads conflict-free.
//   3) GRU on the re-read A-fragments (hbuf round-trip through HBM is gone).
// Gate fusion: r/z accumulate gi+gh+bias in ONE chain of 4 MFMAs each; only
// the n gate keeps separate gi_n/gh_n (r * gh_n). Fast sigmoid/tanh.
// LDS 48+16+8 = 72KB -> 2 blocks/CU; grid 512 = exactly resident.
// ---------------------------------------------------------------------------
#define GRU_TILES (N_NODES / 16)
__global__ __launch_bounds__(256) void k_mixgru(const bf16* __restrict__ gru_pk,
                                                const bf16* __restrict__ mixf_pk,
                                                const float* __restrict__ bfused,
                                                const bf16* __restrict__ agg16,
                                                const float* __restrict__ h_prev,
                                                const float* __restrict__ bih_g,
                                                const float* __restrict__ bhh_g,
                                                const float* __restrict__ Wro_g,
                                                const float* __restrict__ bro_g,
                                                float* __restrict__ out_h,
                                                float* __restrict__ out_o) {
    __shared__ __align__(16) bf16 Wpk[GRU_PK];      // 48 KB
    __shared__ __align__(16) bf16 Wmx[MIX_PK];      // 16 KB
    __shared__ __align__(16) bf16 bounce[4 * 1024]; // 4 waves x 16x64 bf16 = 8 KB
    {
        const bf16x8* src = (const bf16x8*)gru_pk;
        bf16x8* dst = (bf16x8*)Wpk;
        for (int i = threadIdx.x; i < GRU_PK / 8; i += 256) dst[i] = src[i];
        const bf16x8* src2 = (const bf16x8*)mixf_pk;
        bf16x8* dst2 = (bf16x8*)Wmx;
        for (int i = threadIdx.x; i < MIX_PK / 8; i += 256) dst2[i] = src2[i];
    }
    __syncthreads();

    int wid = threadIdx.x >> 6, lane = threadIdx.x & 63;
    int quad = lane >> 4, l16 = lane & 15;
    bf16* bnc = &bounce[wid * 1024];

    float bmv[4];
#pragma unroll
    for (int ct = 0; ct < 4; ++ct) bmv[ct] = bfused[ct * 16 + l16];

    float br_c[4], bz_c[4], bin_c[4], bhn_c[4], wv[4][3];
#pragma unroll
    for (int cc = 0; cc < 4; ++cc) {
        int col = cc * 16 + l16;
        br_c[cc] = bih_g[col] + bhh_g[col];
        bz_c[cc] = bih_g[64 + col] + bhh_g[64 + col];
        bin_c[cc] = bih_g[128 + col];
        bhn_c[cc] = bhh_g[128 + col];
        wv[cc][0] = Wro_g[col * 64 + 0];
        wv[cc][1] = Wro_g[col * 64 + 1];
        wv[cc][2] = Wro_g[col * 64 + 2];
    }
    float bro0 = bro_g[0], bro1 = bro_g[1], bro2 = bro_g[2];

    int wave = blockIdx.x * 4 + wid;
    int n_waves = gridDim.x * 4;

    for (int tile = wave; tile < GRU_TILES; tile += n_waves) {
        int row0 = tile * 16;
        int arow = row0 + l16;

        // ---- mix ----
        bf16x8 af[4];
#pragma unroll
        for (int kt = 0; kt < 4; ++kt) {
            const bf16* src = (kt < 2)
                ? agg16 + (size_t)arow * 64 + kt * 32 + quad * 8
                : agg16 + ((size_t)N_NODES + arow) * 64 + (kt - 2) * 32 + quad * 8;
            af[kt] = *(const bf16x8*)src;
        }
#define LDBM(kt, ct) (*(const bf16x8*)&Wmx[(((kt)*4 + (ct)) * 64 + lane) * 8])
#pragma unroll
        for (int ct = 0; ct < 4; ++ct) {
            f32x4 acc = {bmv[ct], bmv[ct], bmv[ct], bmv[ct]};
#pragma unroll
            for (int kt = 0; kt < 4; ++kt)
                acc = __builtin_amdgcn_mfma_f32_16x16x32_bf16(af[kt], LDBM(kt, ct), acc, 0, 0, 0);
            // D-layout store into per-wave bounce, chunk-XOR swizzled.
#pragma unroll
            for (int rg = 0; rg < 4; ++rg) {
                int r = quad * 4 + rg;                       // local row
                int chunk = ct * 2 + (l16 >> 3);             // 8-col chunk
                int cs = chunk ^ (r & 7);                    // swizzled
                bnc[r * 64 + cs * 8 + (l16 & 7)] = f2b(fmaxf(acc[rg], 0.f));
            }
        }
#undef LDBM
        asm volatile("s_waitcnt lgkmcnt(0)" ::: "memory");
        __builtin_amdgcn_sched_barrier(0);

        // ---- re-read as A-fragments (row l16, chunks quad / quad+4) ----
        bf16x8 ha0 = *(const bf16x8*)&bnc[l16 * 64 + (quad ^ (l16 & 7)) * 8];
        bf16x8 ha1 = *(const bf16x8*)&bnc[l16 * 64 + ((quad + 4) ^ (l16 & 7)) * 8];

        const float* pp = h_prev + (size_t)arow * 64 + quad * 8;
        bf16x8 pa0 = pack8(*(const float4*)pp, *(const float4*)(pp + 4));
        bf16x8 pa1 = pack8(*(const float4*)(pp + 32), *(const float4*)(pp + 36));

        float p[4][3];
#pragma unroll
        for (int rg = 0; rg < 4; ++rg) p[rg][0] = p[rg][1] = p[rg][2] = 0.f;

#pragma unroll
        for (int cc = 0; cc < 4; ++cc) {
#define LDB(mat, kt, ct) (*(const bf16x8*)&Wpk[((((mat)*2 + (kt)) * 12 + (ct)) * 64 + lane) * 8])
            f32x4 rs = {br_c[cc], br_c[cc], br_c[cc], br_c[cc]};
            f32x4 zs = {bz_c[cc], bz_c[cc], bz_c[cc], bz_c[cc]};
            f32x4 gin = {bin_c[cc], bin_c[cc], bin_c[cc], bin_c[cc]};
            f32x4 ghn = {bhn_c[cc], bhn_c[cc], bhn_c[cc], bhn_c[cc]};
            rs = __builtin_amdgcn_mfma_f32_16x16x32_bf16(ha0, LDB(0, 0, cc), rs, 0, 0, 0);
            rs = __builtin_amdgcn_mfma_f32_16x16x32_bf16(ha1, LDB(0, 1, cc), rs, 0, 0, 0);
            rs = __builtin_amdgcn_mfma_f32_16x16x32_bf16(pa0, LDB(1, 0, cc), rs, 0, 0, 0);
            rs = __builtin_amdgcn_mfma_f32_16x16x32_bf16(pa1, LDB(1, 1, cc), rs, 0, 0, 0);
            zs = __builtin_amdgcn_mfma_f32_16x16x32_bf16(ha0, LDB(0, 0, cc + 4), zs, 0, 0, 0);
            zs = __builtin_amdgcn_mfma_f32_16x16x32_bf16(ha1, LDB(0, 1, cc + 4), zs, 0, 0, 0);
            zs = __builtin_amdgcn_mfma_f32_16x16x32_bf16(pa0, LDB(1, 0, cc + 4), zs, 0, 0, 0);
            zs = __builtin_amdgcn_mfma_f32_16x16x32_bf16(pa1, LDB(1, 1, cc + 4), zs, 0, 0, 0);
            gin = __builtin_amdgcn_mfma_f32_16x16x32_bf16(ha0, LDB(0, 0, cc + 8), gin, 0, 0, 0);
            gin = __builtin_amdgcn_mfma_f32_16x16x32_bf16(ha1, LDB(0, 1, cc + 8), gin, 0, 0, 0);
            ghn = __builtin_amdgcn_mfma_f32_16x16x32_bf16(pa0, LDB(1, 0, cc + 8), ghn, 0, 0, 0);
            ghn = __builtin_amdgcn_mfma_f32_16x16x32_bf16(pa1, LDB(1, 1, cc + 8), ghn, 0, 0, 0);
#undef LDB
#pragma unroll
            for (int rg = 0; rg < 4; ++rg) {
                int row = row0 + quad * 4 + rg;
                float pv = h_prev[(size_t)row * 64 + cc * 16 + l16];
                float rr = fast_sigmoid(rs[rg]);
                float zz = fast_sigmoid(zs[rg]);
                float nn = fast_tanh(gin[rg] + rr * ghn[rg]);
                float hn = (1.f - zz) * nn + zz * pv;
                out_h[(size_t)row * 64 + cc * 16 + l16] = hn;
                p[rg][0] += hn * wv[cc][0];
                p[rg][1] += hn * wv[cc][1];
                p[rg][2] += hn * wv[cc][2];
            }
        }
#pragma unroll
        for (int rg = 0; rg < 4; ++rg) {
#pragma unroll
            for (int m = 1; m < 16; m <<= 1) {
                p[rg][0] += __shfl_xor(p[rg][0], m);
                p[rg][1] += __shfl_xor(p[rg][1], m);
                p[rg][2] += __shfl_xor(p[rg][2], m);
            }
        }
        if (l16 == 0) {
#pragma unroll
            for (int rg = 0; rg < 4; ++rg) {
                int row = row0 + quad * 4 + rg;
                out_o[(size_t)row * 3 + 0] = p[rg][0] + bro0;
                out_o[(size_t)row * 3 + 1] = p[rg][1] + bro1;
                out_o[(size_t)row * 3 + 2] = p[rg][2] + bro2;
            }
        }
    }
}

extern "C" void kernel_launch(void* const* d_in, const int* in_sizes, int n_in,
                              void* d_out, int out_size, void* d_ws, size_t ws_size,
                              hipStream_t stream) {
    const float* x        = (const float*)d_in[0];
    const float* h_prev   = (const float*)d_in[1];
    const int* node_idx   = (const int*)d_in[2];
    const int* hedge_idx  = (const int*)d_in[3];
    const int* edge_attr  = (const int*)d_in[4];
    const float* W_conv   = (const float*)d_in[5];
    const float* b_conv   = (const float*)d_in[6];
    const float* W_mix    = (const float*)d_in[7];
    const float* b_mix    = (const float*)d_in[8];
    const float* W_ih     = (const float*)d_in[9];
    const float* W_hh     = (const float*)d_in[10];
    const float* b_ih     = (const float*)d_in[11];
    const float* b_hh     = (const float*)d_in[12];
    const float* W_ro     = (const float*)d_in[13];
    const float* b_ro     = (const float*)d_in[14];

    char* p = (char*)d_ws;
    auto alloc = [&](size_t bytes) {
        char* r = p;
        p += (bytes + 63) & ~(size_t)63;
        return r;
    };
    // Region A: scan scratch (cnt/off/bsum, dead after k_scan3) overlaid
    // by agg16 (written in k_no2). 25.6MB >= 15.4MB scan need.
    char* regA     = alloc((size_t)2 * N_NODES * 64 * 2);
    int* cnt       = (int*)regA;
    int* off       = cnt + TOT;
    int* bsum      = off + TOT + 1;
    bf16* agg16    = (bf16*)regA;
    int* offT      = (int*)alloc((size_t)(MSEG + 1) * NSUB * 4);
    int* sortedAll = (int*)alloc((size_t)2 * N_EDGES * 4);
    int* r1        = (int*)alloc((size_t)N_EDGES * 4);
    int* r2        = (int*)alloc((size_t)N_EDGES * 4);
    bf16* xb       = (bf16*)alloc((size_t)N_NODES * 64 * 2);
    bf16* ef16     = (bf16*)alloc((size_t)HSEG * 64 * 2);
    bf16* gru_pk   = (bf16*)alloc((size_t)GRU_PK * 2);
    bf16* mixf_pk  = (bf16*)alloc((size_t)MIX_PK * 2);
    float* bfused  = (float*)alloc(64 * 4);

    hipMemsetAsync(cnt, 0, (size_t)TOT * 4, stream);

    float* out_h = (float*)d_out;
    float* out_o = out_h + (size_t)N_NODES * 64;

    k_pack<<<16, 256, 0, stream>>>(W_conv, W_mix, b_conv, b_mix, W_ih, W_hh,
                                   gru_pk, mixf_pk, bfused);
    k_cast<<<(N_NODES * 64 / 8 + 255) / 256, 256, 0, stream>>>(x, xb);
    k_hist<<<HIST_THREADS / 256, 256, 0, stream>>>(node_idx, hedge_idx, edge_attr,
                                                   cnt, r1, r2);
    k_scan1<<<SCAN_BLOCKS, 256, 0, stream>>>(cnt, off, bsum);
    k_scan2<<<1, 1024, 0, stream>>>(bsum);
    k_scan3<<<SCAN_BLOCKS, 256, 0, stream>>>(off, bsum, offT);
    k_scatter<<<(N_EDGES + 255) / 256, 256, 0, stream>>>(node_idx, hedge_idx, edge_attr,
                                                         offT, r1, r2, sortedAll);
    k_ef2<<<HSEG / 16, 256, 0, stream>>>(offT, sortedAll, xb, ef16);
    k_no2<<<NSEG / 16, 256, 0, stream>>>(offT, sortedAll, ef16, agg16);
    k_mixgru<<<512, 256, 0, stream>>>(gru_pk, mixf_pk, bfused, agg16, h_prev,
                                      b_ih, b_hh, W_ro, b_ro, out_h, out_o);
}

// Round 5
// 317.117 us; speedup vs baseline: 1.7745x; 1.2506x over previous
//
#include <hip/hip_runtime.h>
#include <hip/hip_bf16.h>

#define N_NODES 100000
#define N_HEDGES 20000
#define N_EDGES 800000
#define HSEG (2 * N_HEDGES)            // 40000 hedge segments (t,h)
#define NSEG (2 * N_NODES)             // 200000 node segments (t,n)
#define MSEG (HSEG + NSEG)             // 240000 segments
#define TOT MSEG                        // one counter per segment (NSUB=1:
                                        // atomics bypass L2 anyway — round-4
                                        // PMC proved sub-privatization moot)
#define SCAN_BLOCKS ((TOT + 2047) / 2048)  // 118

#define MIX_PK  (4 * 4 * 64 * 8)        // 8192 packed bf16 fused-mix weights
#define GRU_PK  (2 * 2 * 12 * 64 * 8)   // 24576 for k_gru

typedef __hip_bfloat16 bf16;
typedef __attribute__((ext_vector_type(8))) short bf16x8;
typedef __attribute__((ext_vector_type(4))) float f32x4;

__device__ __forceinline__ float b2f(bf16 v) { return __bfloat162float(v); }
__device__ __forceinline__ bf16 f2b(float v) { return __float2bfloat16(v); }
__device__ __forceinline__ short f2s(float v) {
    bf16 b = __float2bfloat16(v);
    return *reinterpret_cast<short*>(&b);
}
__device__ __forceinline__ uint pk2(float a, float b) {
    return (uint)(unsigned short)f2s(a) | ((uint)(unsigned short)f2s(b) << 16);
}
__device__ __forceinline__ bf16x8 pack8(float4 a, float4 b) {
    bf16x8 r = {f2s(a.x), f2s(a.y), f2s(a.z), f2s(a.w),
                f2s(b.x), f2s(b.y), f2s(b.z), f2s(b.w)};
    return r;
}
__device__ __forceinline__ float fast_sigmoid(float x) {
    return __builtin_amdgcn_rcpf(1.f + __expf(-x));
}
__device__ __forceinline__ float fast_tanh(float x) {
    return 1.f - 2.f * __builtin_amdgcn_rcpf(1.f + __expf(2.f * x));
}

// ---------------------------------------------------------------------------
// Pack GRU weights into LDS layout; compute FUSED mix weights on device:
//   Wf[t] = W_conv[t] @ W_mix[t*64:(t+1)*64, :]   (64x64 each, f32 dot, bf16)
//   bfused = b_mix + sum_t b_conv[t] @ W_mix_t
// ---------------------------------------------------------------------------
__global__ __launch_bounds__(256) void k_pack(const float* __restrict__ Wc,
                                              const float* __restrict__ Wm,
                                              const float* __restrict__ bc,
                                              const float* __restrict__ bm,
                                              const float* __restrict__ Wih,
                                              const float* __restrict__ Whh,
                                              bf16* __restrict__ gru_pk,
                                              bf16* __restrict__ mixf_pk,
                                              float* __restrict__ bfused) {
    int idx = blockIdx.x * 256 + threadIdx.x;
    int stride = gridDim.x * 256;
    for (int i = idx; i < GRU_PK; i += stride) {
        int j = i & 7;
        int r = i >> 3;
        int ln = r & 63;
        int r2 = r >> 6;
        int ct = r2 % 12;
        int r3 = r2 / 12;
        int kt = r3 & 1;
        int mat = r3 >> 1;
        int k = kt * 32 + ((ln >> 4) << 3) + j;
        int n = ct * 16 + (ln & 15);
        float v = mat == 0 ? Wih[k * 192 + n] : Whh[k * 192 + n];
        gru_pk[i] = f2b(v);
    }
    for (int i = idx; i < MIX_PK; i += stride) {
        int j = i & 7, ln = (i >> 3) & 63, r2 = i >> 9;
        int ct = r2 & 3, kt = r2 >> 2;
        int k = kt * 32 + ((ln >> 4) << 3) + j;   // 0..127 (concat dim)
        int n = ct * 16 + (ln & 15);
        int t = k >> 6, kk = k & 63;
        float s = 0.f;
        for (int q = 0; q < 64; ++q)
            s += Wc[((size_t)t * 64 + kk) * 64 + q] * Wm[(size_t)(t * 64 + q) * 64 + n];
        mixf_pk[i] = f2b(s);
    }
    for (int i = idx; i < 64; i += stride) {
        float s = bm[i];
        for (int q = 0; q < 64; ++q)
            s += bc[q] * Wm[(size_t)q * 64 + i] + bc[64 + q] * Wm[(size_t)(64 + q) * 64 + i];
        bfused[i] = s;
    }
}

// ---------------------------------------------------------------------------
// Cast x to bf16 once; gathers then read 128B rows shared by both types.
// ---------------------------------------------------------------------------
__global__ __launch_bounds__(256) void k_cast(const float* __restrict__ x,
                                              bf16* __restrict__ xb) {
    size_t i = ((size_t)blockIdx.x * 256 + threadIdx.x) * 8;
    const float* xp = x + i;
    float4 a = *(const float4*)xp;
    float4 b = *(const float4*)(xp + 4);
    *(bf16x8*)(xb + i) = pack8(a, b);
}

// ---------------------------------------------------------------------------
// Histogram: one counter per segment. The atomicAdd return IS the edge's
// rank within its segment — recorded so k_scatter needs no atomics.
// Bound: memory-side atomic transaction throughput (~25G/s measured); ILP
// variants are neutral (round-4 A/B), so keep the simple form.
// ---------------------------------------------------------------------------
__global__ __launch_bounds__(256) void k_hist(const int* __restrict__ node_idx,
                                              const int* __restrict__ hedge_idx,
                                              const int* __restrict__ attr,
                                              int* __restrict__ cnt,
                                              int* __restrict__ r1,
                                              int* __restrict__ r2) {
    int e = blockIdx.x * 256 + threadIdx.x;
    if (e < N_EDGES) {
        int t = attr[e];
        r1[e] = atomicAdd(&cnt[t * N_HEDGES + hedge_idx[e]], 1);
        r2[e] = atomicAdd(&cnt[HSEG + t * N_NODES + node_idx[e]], 1);
    }
}

// ---------------------------------------------------------------------------
// Scan 1/3: 2048 elems/block (256 thr x 8), partial exclusive scan + bsum.
// ---------------------------------------------------------------------------
__global__ __launch_bounds__(256) void k_scan1(const int* __restrict__ cnt,
                                               int* __restrict__ off,
                                               int* __restrict__ bsum) {
    __shared__ int s[256];
    int base = blockIdx.x * 2048 + threadIdx.x * 8;
    int v[8];
    int tsum = 0;
#pragma unroll
    for (int j = 0; j < 8; ++j) {
        int g = base + j;
        v[j] = (g < TOT) ? cnt[g] : 0;
        tsum += v[j];
    }
    s[threadIdx.x] = tsum;
    __syncthreads();
    for (int o = 1; o < 256; o <<= 1) {
        int t = (threadIdx.x >= o) ? s[threadIdx.x - o] : 0;
        __syncthreads();
        s[threadIdx.x] += t;
        __syncthreads();
    }
    int run = s[threadIdx.x] - tsum;
#pragma unroll
    for (int j = 0; j < 8; ++j) {
        int g = base + j;
        if (g < TOT) off[g] = run;
        run += v[j];
    }
    if (threadIdx.x == 255) bsum[blockIdx.x] = s[255];
}

// ---------------------------------------------------------------------------
// Scan 2/3: exclusive scan of SCAN_BLOCKS (<=1024) block sums, one block.
// ---------------------------------------------------------------------------
__global__ __launch_bounds__(1024) void k_scan2(int* __restrict__ bsum) {
    __shared__ int s[1024];
    int tid = threadIdx.x;
    int v = (tid < SCAN_BLOCKS) ? bsum[tid] : 0;
    s[tid] = v;
    __syncthreads();
    for (int o = 1; o < 1024; o <<= 1) {
        int t = (tid >= o) ? s[tid - o] : 0;
        __syncthreads();
        s[tid] += t;
        __syncthreads();
    }
    if (tid < SCAN_BLOCKS) bsum[tid] = s[tid] - v;
}

// ---------------------------------------------------------------------------
// Scan 3/3: finalize off in place (+ sentinel off[TOT] = 2*N_EDGES).
// off IS the CSR row-pointer array used by scatter and both gathers.
// ---------------------------------------------------------------------------
__global__ __launch_bounds__(256) void k_scan3(int* __restrict__ off,
                                               const int* __restrict__ bsum) {
    int base = blockIdx.x * 2048 + threadIdx.x * 8;
    int add = bsum[blockIdx.x];
#pragma unroll
    for (int j = 0; j < 8; ++j) {
        int g = base + j;
        if (g < TOT) off[g] += add;
    }
    if (blockIdx.x == 0 && threadIdx.x == 0) off[TOT] = 2 * N_EDGES;
}

// ---------------------------------------------------------------------------
// Scatter, ATOMIC-FREE: position = off[seg] + rank recorded by k_hist.
// ---------------------------------------------------------------------------
__global__ __launch_bounds__(256) void k_scatter(const int* __restrict__ node_idx,
                                                 const int* __restrict__ hedge_idx,
                                                 const int* __restrict__ attr,
                                                 const int* __restrict__ off,
                                                 const int* __restrict__ r1,
                                                 const int* __restrict__ r2,
                                                 int* __restrict__ sortedAll) {
    int e = blockIdx.x * 256 + threadIdx.x;
    if (e < N_EDGES) {
        int t = attr[e], n = node_idx[e], h = hedge_idx[e];
        int p1 = off[t * N_HEDGES + h] + r1[e];
        sortedAll[p1] = n;
        int p2 = off[HSEG + t * N_NODES + n] + r2[e];
        sortedAll[p2] = t * N_HEDGES + h;
    }
}

// ---------------------------------------------------------------------------
// Quarter-per-segment gather, single contiguous run per segment (NSUB=1).
// Within a quarter: 8-lane half-groups process even/odd list elements with
// uint4 (16B/lane) row reads — 2 rows (256B) in flight per quarter per iter,
// HALF the dependent loads of the old 16-lane x 8B form. Epilogue combines
// halves with one shfl_xor(8); lanes 0..7 of each quarter store one 16B
// chunk -> 128B row store per segment.
// ---------------------------------------------------------------------------
__device__ __forceinline__ void seg_gather(const int* __restrict__ off,
                                           const int* __restrict__ sortedAll,
                                           const bf16* __restrict__ rows,
                                           int seg0, int lane,
                                           float acc[8], int* total) {
    int q = lane >> 4, l16 = lane & 15;
    int ov = 0;
    if (lane < 5) ov = off[seg0 + lane];   // 4 consecutive segs: begs+ends
    int myb = __shfl(ov, q);
    int mye = __shfl(ov, q + 1);
#pragma unroll
    for (int j = 0; j < 8; ++j) acc[j] = 0.f;
    for (int i = myb + (l16 >> 3); i < mye; i += 2) {
        int idx = sortedAll[i];            // broadcast within 8-lane group
        uint4 v = *(const uint4*)(rows + (size_t)idx * 64 + (l16 & 7) * 8);
        acc[0] += __uint_as_float(v.x << 16);
        acc[1] += __uint_as_float(v.x & 0xffff0000u);
        acc[2] += __uint_as_float(v.y << 16);
        acc[3] += __uint_as_float(v.y & 0xffff0000u);
        acc[4] += __uint_as_float(v.z << 16);
        acc[5] += __uint_as_float(v.z & 0xffff0000u);
        acc[6] += __uint_as_float(v.w << 16);
        acc[7] += __uint_as_float(v.w & 0xffff0000u);
    }
#pragma unroll
    for (int j = 0; j < 8; ++j) acc[j] += __shfl_xor(acc[j], 8);
    *total = mye - myb;
}

// CSR node->hedge: ef_raw[t][h] = (1/B) * sum xb rows (RAW x, no weights).
__global__ __launch_bounds__(256) void k_ef2(const int* __restrict__ off,
                                             const int* __restrict__ sortedAll,
                                             const bf16* __restrict__ xb,
                                             bf16* __restrict__ ef16) {
    int wid = threadIdx.x >> 6, lane = threadIdx.x & 63;
    int seg0 = (blockIdx.x * 4 + wid) * 4;
    if (seg0 >= HSEG) return;
    float acc[8];
    int tot;
    seg_gather(off, sortedAll, xb, seg0, lane, acc, &tot);
    float scale = tot > 0 ? 1.0f / (float)tot : 0.f;
    int q = lane >> 4, l16 = lane & 15;
    if (l16 < 8) {
        int s = seg0 + q;
        uint4 w;
        w.x = pk2(acc[0] * scale, acc[1] * scale);
        w.y = pk2(acc[2] * scale, acc[3] * scale);
        w.z = pk2(acc[4] * scale, acc[5] * scale);
        w.w = pk2(acc[6] * scale, acc[7] * scale);
        *(uint4*)(ef16 + (size_t)s * 64 + l16 * 8) = w;
    }
}

// CSR hedge->node: agg[t][n] = (1/D) * sum ef_raw rows. Bias folded into
// bfused (k_mixgru), so no add here.
__global__ __launch_bounds__(256) void k_no2(const int* __restrict__ off,
                                             const int* __restrict__ sortedAll,
                                             const bf16* __restrict__ ef16,
                                             bf16* __restrict__ agg16) {
    int wid = threadIdx.x >> 6, lane = threadIdx.x & 63;
    int j0 = (blockIdx.x * 4 + wid) * 4;
    if (j0 >= NSEG) return;
    float acc[8];
    int tot;
    seg_gather(off, sortedAll, ef16, HSEG + j0, lane, acc, &tot);
    float scale = tot > 0 ? 1.0f / (float)tot : 0.f;
    int q = lane >> 4, l16 = lane & 15;
    if (l16 < 8) {
        int j = j0 + q;
        uint4 w;
        w.x = pk2(acc[0] * scale, acc[1] * scale);
        w.y = pk2(acc[2] * scale, acc[3] * scale);
        w.z = pk2(acc[4] * scale, acc[5] * scale);
        w.w = pk2(acc[6] * scale, acc[7] * scale);
        *(uint4*)(agg16 + (size_t)j * 64 + l16 * 8) = w;
    }
}

// ---------------------------------------------------------------------------
// FUSED mix+GRU (unchanged from round 4 — passed). Per 16-row tile:
// mix MFMA -> per-wave LDS bounce (chunk-XOR swizzle, same-wave DS order) ->
// GRU MFMA chains (r/z gates fused gi+gh+bias), fast sigmoid/tanh.
// ---------------------------------------------------------------------------
#define GRU_TILES (N_NODES / 16)
__global__ __launch_bounds__(256) void k_mixgru(const bf16* __restrict__ gru_pk,
                                                const bf16* __restrict__ mixf_pk,
                                                const float* __restrict__ bfused,
                                                const bf16* __restrict__ agg16,
                                                const float* __restrict__ h_prev,
                                                const float* __restrict__ bih_g,
                                                const float* __restrict__ bhh_g,
                                                const float* __restrict__ Wro_g,
                                                const float* __restrict__ bro_g,
                                                float* __restrict__ out_h,
                                                float* __restrict__ out_o) {
    __shared__ __align__(16) bf16 Wpk[GRU_PK];      // 48 KB
    __shared__ __align__(16) bf16 Wmx[MIX_PK];      // 16 KB
    __shared__ __align__(16) bf16 bounce[4 * 1024]; // 4 waves x 16x64 bf16 = 8 KB
    {
        const bf16x8* src = (const bf16x8*)gru_pk;
        bf16x8* dst = (bf16x8*)Wpk;
        for (int i = threadIdx.x; i < GRU_PK / 8; i += 256) dst[i] = src[i];
        const bf16x8* src2 = (const bf16x8*)mixf_pk;
        bf16x8* dst2 = (bf16x8*)Wmx;
        for (int i = threadIdx.x; i < MIX_PK / 8; i += 256) dst2[i] = src2[i];
    }
    __syncthreads();

    int wid = threadIdx.x >> 6, lane = threadIdx.x & 63;
    int quad = lane >> 4, l16 = lane & 15;
    bf16* bnc = &bounce[wid * 1024];

    float bmv[4];
#pragma unroll
    for (int ct = 0; ct < 4; ++ct) bmv[ct] = bfused[ct * 16 + l16];

    float br_c[4], bz_c[4], bin_c[4], bhn_c[4], wv[4][3];
#pragma unroll
    for (int cc = 0; cc < 4; ++cc) {
        int col = cc * 16 + l16;
        br_c[cc] = bih_g[col] + bhh_g[col];
        bz_c[cc] = bih_g[64 + col] + bhh_g[64 + col];
        bin_c[cc] = bih_g[128 + col];
        bhn_c[cc] = bhh_g[128 + col];
        wv[cc][0] = Wro_g[col * 64 + 0];
        wv[cc][1] = Wro_g[col * 64 + 1];
        wv[cc][2] = Wro_g[col * 64 + 2];
    }
    float bro0 = bro_g[0], bro1 = bro_g[1], bro2 = bro_g[2];

    int wave = blockIdx.x * 4 + wid;
    int n_waves = gridDim.x * 4;

    for (int tile = wave; tile < GRU_TILES; tile += n_waves) {
        int row0 = tile * 16;
        int arow = row0 + l16;

        // ---- mix ----
        bf16x8 af[4];
#pragma unroll
        for (int kt = 0; kt < 4; ++kt) {
            const bf16* src = (kt < 2)
                ? agg16 + (size_t)arow * 64 + kt * 32 + quad * 8
                : agg16 + ((size_t)N_NODES + arow) * 64 + (kt - 2) * 32 + quad * 8;
            af[kt] = *(const bf16x8*)src;
        }
#define LDBM(kt, ct) (*(const bf16x8*)&Wmx[(((kt)*4 + (ct)) * 64 + lane) * 8])
#pragma unroll
        for (int ct = 0; ct < 4; ++ct) {
            f32x4 acc = {bmv[ct], bmv[ct], bmv[ct], bmv[ct]};
#pragma unroll
            for (int kt = 0; kt < 4; ++kt)
                acc = __builtin_amdgcn_mfma_f32_16x16x32_bf16(af[kt], LDBM(kt, ct), acc, 0, 0, 0);
            // D-layout store into per-wave bounce, chunk-XOR swizzled.
#pragma unroll
            for (int rg = 0; rg < 4; ++rg) {
                int r = quad * 4 + rg;                       // local row
                int chunk = ct * 2 + (l16 >> 3);             // 8-col chunk
                int cs = chunk ^ (r & 7);                    // swizzled
                bnc[r * 64 + cs * 8 + (l16 & 7)] = f2b(fmaxf(acc[rg], 0.f));
            }
        }
#undef LDBM
        asm volatile("s_waitcnt lgkmcnt(0)" ::: "memory");
        __builtin_amdgcn_sched_barrier(0);

        // ---- re-read as A-fragments (row l16, chunks quad / quad+4) ----
        bf16x8 ha0 = *(const bf16x8*)&bnc[l16 * 64 + (quad ^ (l16 & 7)) * 8];
        bf16x8 ha1 = *(const bf16x8*)&bnc[l16 * 64 + ((quad + 4) ^ (l16 & 7)) * 8];

        const float* pp = h_prev + (size_t)arow * 64 + quad * 8;
        bf16x8 pa0 = pack8(*(const float4*)pp, *(const float4*)(pp + 4));
        bf16x8 pa1 = pack8(*(const float4*)(pp + 32), *(const float4*)(pp + 36));

        float p[4][3];
#pragma unroll
        for (int rg = 0; rg < 4; ++rg) p[rg][0] = p[rg][1] = p[rg][2] = 0.f;

#pragma unroll
        for (int cc = 0; cc < 4; ++cc) {
#define LDB(mat, kt, ct) (*(const bf16x8*)&Wpk[((((mat)*2 + (kt)) * 12 + (ct)) * 64 + lane) * 8])
            f32x4 rs = {br_c[cc], br_c[cc], br_c[cc], br_c[cc]};
            f32x4 zs = {bz_c[cc], bz_c[cc], bz_c[cc], bz_c[cc]};
            f32x4 gin = {bin_c[cc], bin_c[cc], bin_c[cc], bin_c[cc]};
            f32x4 ghn = {bhn_c[cc], bhn_c[cc], bhn_c[cc], bhn_c[cc]};
            rs = __builtin_amdgcn_mfma_f32_16x16x32_bf16(ha0, LDB(0, 0, cc), rs, 0, 0, 0);
            rs = __builtin_amdgcn_mfma_f32_16x16x32_bf16(ha1, LDB(0, 1, cc), rs, 0, 0, 0);
            rs = __builtin_amdgcn_mfma_f32_16x16x32_bf16(pa0, LDB(1, 0, cc), rs, 0, 0, 0);
            rs = __builtin_amdgcn_mfma_f32_16x16x32_bf16(pa1, LDB(1, 1, cc), rs, 0, 0, 0);
            zs = __builtin_amdgcn_mfma_f32_16x16x32_bf16(ha0, LDB(0, 0, cc + 4), zs, 0, 0, 0);
            zs = __builtin_amdgcn_mfma_f32_16x16x32_bf16(ha1, LDB(0, 1, cc + 4), zs, 0, 0, 0);
            zs = __builtin_amdgcn_mfma_f32_16x16x32_bf16(pa0, LDB(1, 0, cc + 4), zs, 0, 0, 0);
            zs = __builtin_amdgcn_mfma_f32_16x16x32_bf16(pa1, LDB(1, 1, cc + 4), zs, 0, 0, 0);
            gin = __builtin_amdgcn_mfma_f32_16x16x32_bf16(ha0, LDB(0, 0, cc + 8), gin, 0, 0, 0);
            gin = __builtin_amdgcn_mfma_f32_16x16x32_bf16(ha1, LDB(0, 1, cc + 8), gin, 0, 0, 0);
            ghn = __builtin_amdgcn_mfma_f32_16x16x32_bf16(pa0, LDB(1, 0, cc + 8), ghn, 0, 0, 0);
            ghn = __builtin_amdgcn_mfma_f32_16x16x32_bf16(pa1, LDB(1, 1, cc + 8), ghn, 0, 0, 0);
#undef LDB
#pragma unroll
            for (int rg = 0; rg < 4; ++rg) {
                int row = row0 + quad * 4 + rg;
                float pv = h_prev[(size_t)row * 64 + cc * 16 + l16];
                float rr = fast_sigmoid(rs[rg]);
                float zz = fast_sigmoid(zs[rg]);
                float nn = fast_tanh(gin[rg] + rr * ghn[rg]);
                float hn = (1.f - zz) * nn + zz * pv;
                out_h[(size_t)row * 64 + cc * 16 + l16] = hn;
                p[rg][0] += hn * wv[cc][0];
                p[rg][1] += hn * wv[cc][1];
                p[rg][2] += hn * wv[cc][2];
            }
        }
#pragma unroll
        for (int rg = 0; rg < 4; ++rg) {
#pragma unroll
            for (int m = 1; m < 16; m <<= 1) {
                p[rg][0] += __shfl_xor(p[rg][0], m);
                p[rg][1] += __shfl_xor(p[rg][1], m);
                p[rg][2] += __shfl_xor(p[rg][2], m);
            }
        }
        if (l16 == 0) {
#pragma unroll
            for (int rg = 0; rg < 4; ++rg) {
                int row = row0 + quad * 4 + rg;
                out_o[(size_t)row * 3 + 0] = p[rg][0] + bro0;
                out_o[(size_t)row * 3 + 1] = p[rg][1] + bro1;
                out_o[(size_t)row * 3 + 2] = p[rg][2] + bro2;
            }
        }
    }
}

extern "C" void kernel_launch(void* const* d_in, const int* in_sizes, int n_in,
                              void* d_out, int out_size, void* d_ws, size_t ws_size,
                              hipStream_t stream) {
    const float* x        = (const float*)d_in[0];
    const float* h_prev   = (const float*)d_in[1];
    const int* node_idx   = (const int*)d_in[2];
    const int* hedge_idx  = (const int*)d_in[3];
    const int* edge_attr  = (const int*)d_in[4];
    const float* W_conv   = (const float*)d_in[5];
    const float* b_conv   = (const float*)d_in[6];
    const float* W_mix    = (const float*)d_in[7];
    const float* b_mix    = (const float*)d_in[8];
    const float* W_ih     = (const float*)d_in[9];
    const float* W_hh     = (const float*)d_in[10];
    const float* b_ih     = (const float*)d_in[11];
    const float* b_hh     = (const float*)d_in[12];
    const float* W_ro     = (const float*)d_in[13];
    const float* b_ro     = (const float*)d_in[14];

    char* p = (char*)d_ws;
    auto alloc = [&](size_t bytes) {
        char* r = p;
        p += (bytes + 63) & ~(size_t)63;
        return r;
    };
    // Region A: cnt (dead after k_scan1) + bsum (dead after k_scan3),
    // overlaid by agg16 (first written in k_no2). off is the LIVE CSR
    // row-pointer array -> separate allocation.
    char* regA     = alloc((size_t)2 * N_NODES * 64 * 2);   // 25.6 MB
    int* cnt       = (int*)regA;
    int* bsum      = cnt + TOT;
    bf16* agg16    = (bf16*)regA;
    int* off       = (int*)alloc((size_t)(TOT + 1) * 4);
    int* sortedAll = (int*)alloc((size_t)2 * N_EDGES * 4);
    int* r1        = (int*)alloc((size_t)N_EDGES * 4);
    int* r2        = (int*)alloc((size_t)N_EDGES * 4);
    bf16* xb       = (bf16*)alloc((size_t)N_NODES * 64 * 2);
    bf16* ef16     = (bf16*)alloc((size_t)HSEG * 64 * 2);
    bf16* gru_pk   = (bf16*)alloc((size_t)GRU_PK * 2);
    bf16* mixf_pk  = (bf16*)alloc((size_t)MIX_PK * 2);
    float* bfused  = (float*)alloc(64 * 4);

    hipMemsetAsync(cnt, 0, (size_t)TOT * 4, stream);

    float* out_h = (float*)d_out;
    float* out_o = out_h + (size_t)N_NODES * 64;

    k_pack<<<16, 256, 0, stream>>>(W_conv, W_mix, b_conv, b_mix, W_ih, W_hh,
                                   gru_pk, mixf_pk, bfused);
    k_cast<<<(N_NODES * 64 / 8 + 255) / 256, 256, 0, stream>>>(x, xb);
    k_hist<<<(N_EDGES + 255) / 256, 256, 0, stream>>>(node_idx, hedge_idx, edge_attr,
                                                      cnt, r1, r2);
    k_scan1<<<SCAN_BLOCKS, 256, 0, stream>>>(cnt, off, bsum);
    k_scan2<<<1, 1024, 0, stream>>>(bsum);
    k_scan3<<<SCAN_BLOCKS, 256, 0, stream>>>(off, bsum);
    k_scatter<<<(N_EDGES + 255) / 256, 256, 0, stream>>>(node_idx, hedge_idx, edge_attr,
                                                         off, r1, r2, sortedAll);
    k_ef2<<<HSEG / 16, 256, 0, stream>>>(off, sortedAll, xb, ef16);
    k_no2<<<NSEG / 16, 256, 0, stream>>>(off, sortedAll, ef16, agg16);
    k_mixgru<<<512, 256, 0, stream>>>(gru_pk, mixf_pk, bfused, agg16, h_prev,
                                      b_ih, b_hh, W_ro, b_ro, out_h, out_o);
}